// Round 7
// baseline (735.966 us; speedup 1.0000x reference)
//
#include <hip/hip_runtime.h>
#include <math.h>

// GCN 3-layer + classifier — 2-D binned counting sort + LDS-STAGED-window
// aggregation (round 7).
//
// Empirical law from rounds 1-6: every edge-streaming kernel costs ~130us
// regardless of internals; round-6 windowing failed because ~40 windows were
// live per CU (waves unsynchronized across buckets) and thrashed the 32KB L1.
// Round 7: (a) stage each 1024-node src window into LDS with barriers so the
// per-edge gather becomes ds_read_b128 (no divergent global loads at all);
// (b) fuse degree into pass2 (kills the bdeg edge pass).
//
// Math identity: agg[d] = dinv[d]*( g[d] + sum_{in} g[s] ),  g = dinv*h.

#define RBITS 12
#define RNGD  (1 << RBITS)       // 4096 dst nodes per bin
#define NRD_MAX 49
#define SBITS 10
#define SW    (1 << SBITS)       // 1024 src nodes per window (== PB)
#define NS_MAX 200
#define CAP1  133120             // edges per dst bin (mean 131072 + 5.7 sigma)
#define CAP2  896                // edges per (dst,src) bucket (mean 671 + 8.7 sigma)
#define SL    10                 // aggregation slices per dst bin
#define PB    1024
#define EPT1  8
#define EPB1  (PB * EPT1)        // 8192 edges per pass1 block
#define P2BUF 8448               // >= ceil(CAP1/16)

// ---------------- cursors ----------------

__global__ void k_initcur2d(int* __restrict__ c1, int* __restrict__ c2) {
    int t = blockIdx.x * blockDim.x + threadIdx.x;
    if (t < NRD_MAX) c1[t * 16] = t * CAP1;
    if (t < NRD_MAX * NS_MAX) c2[t * 16] = t * CAP2;
}

// ---------------- pass1: bin by dst-range ----------------

__global__ __launch_bounds__(PB) void k_pass1(const int* __restrict__ src,
                                              const int* __restrict__ dst,
                                              int* __restrict__ c1,
                                              int* __restrict__ buf1, int e, int nrd) {
    __shared__ int hist[NRD_MAX];
    __shared__ int start[NRD_MAX + 1];
    __shared__ int gbase[NRD_MAX];
    __shared__ int cur[NRD_MAX];
    __shared__ int buf[EPB1];
    int t = threadIdx.x;
    if (t < NRD_MAX) hist[t] = 0;
    __syncthreads();

    int ds[EPT1], sr[EPT1];
    int base = blockIdx.x * EPB1;
#pragma unroll
    for (int k = 0; k < 2; k++) {
        int idx = base + (k * PB + t) * 4;
        if (idx + 3 < e) {
            int4 d4 = *(const int4*)(dst + idx);
            int4 s4 = *(const int4*)(src + idx);
            ds[4*k+0] = d4.x; ds[4*k+1] = d4.y; ds[4*k+2] = d4.z; ds[4*k+3] = d4.w;
            sr[4*k+0] = s4.x; sr[4*k+1] = s4.y; sr[4*k+2] = s4.z; sr[4*k+3] = s4.w;
        } else {
#pragma unroll
            for (int j = 0; j < 4; j++) {
                int i2 = idx + j;
                if (i2 < e) { ds[4*k+j] = dst[i2]; sr[4*k+j] = src[i2]; }
                else ds[4*k+j] = -1;
            }
        }
    }
#pragma unroll
    for (int k = 0; k < EPT1; k++)
        if (ds[k] >= 0) atomicAdd(&hist[ds[k] >> RBITS], 1);
    __syncthreads();

    if (t == 0) {
        int run = 0;
        for (int i = 0; i < nrd; i++) { start[i] = run; run += hist[i]; }
        start[nrd] = run;
    }
    __syncthreads();
    if (t < nrd) {
        cur[t] = start[t];
        gbase[t] = hist[t] ? atomicAdd(&c1[t * 16], hist[t]) : 0;
    }
    __syncthreads();

#pragma unroll
    for (int k = 0; k < EPT1; k++) {
        if (ds[k] >= 0) {
            int bin = ds[k] >> RBITS;
            int p = atomicAdd(&cur[bin], 1);
            buf[p] = (sr[k] << RBITS) | (ds[k] & (RNGD - 1));
        }
    }
    __syncthreads();

    int total = start[nrd];
    for (int j = t; j < total; j += PB) {
        int lo = 0, hi = nrd;
        while (hi - lo > 1) { int mid = (lo + hi) >> 1; if (start[mid] <= j) lo = mid; else hi = mid; }
        int g = gbase[lo] + (j - start[lo]);
        if (g < (lo + 1) * CAP1) buf1[g] = buf[j];
    }
}

// ---------------- pass2: bin each dst-bin by src-window + fused degree ----------------

__global__ __launch_bounds__(PB) void k_pass2(const int* __restrict__ buf1,
                                              const int* __restrict__ c1,
                                              int* __restrict__ c2,
                                              int* __restrict__ csrp,
                                              unsigned short* __restrict__ pdeg, int ns) {
    __shared__ int hist[NS_MAX];
    __shared__ int start[NS_MAX + 1];
    __shared__ int gbase[NS_MAX];
    __shared__ int cur[NS_MAX];
    __shared__ int deg[RNGD];
    __shared__ int buf[P2BUF];
    int t = threadIdx.x;
    int bin = blockIdx.x >> 4, chunk = blockIdx.x & 15;
    int cnt = c1[bin * 16] - bin * CAP1; if (cnt > CAP1) cnt = CAP1;
    int csz = (cnt + 15) >> 4;
    int lo = chunk * csz;
    int hi = lo + csz; if (hi > cnt) hi = cnt;
    int m = hi - lo; if (m < 0) m = 0;
    const int* ebase = buf1 + (size_t)bin * CAP1 + lo;

    for (int i = t; i < NS_MAX; i += PB) hist[i] = 0;
    for (int i = t; i < RNGD; i += PB) deg[i] = 0;
    __syncthreads();

    int pv[9];
#pragma unroll
    for (int k = 0; k < 9; k++) {
        int j = t + k * PB;
        if (j < m) {
            pv[k] = __builtin_nontemporal_load(ebase + j);
            atomicAdd(&hist[pv[k] >> (RBITS + SBITS)], 1);
            atomicAdd(&deg[pv[k] & (RNGD - 1)], 1);
        }
    }
    __syncthreads();

    if (t == 0) {
        int run = 0;
        for (int i = 0; i < ns; i++) { start[i] = run; run += hist[i]; }
        start[ns] = run;
    }
    __syncthreads();
    if (t < ns) {
        cur[t] = start[t];
        gbase[t] = hist[t] ? atomicAdd(&c2[(bin * NS_MAX + t) * 16], hist[t]) : 0;
    }
    __syncthreads();

#pragma unroll
    for (int k = 0; k < 9; k++) {
        int j = t + k * PB;
        if (j < m) {
            int s = pv[k] >> (RBITS + SBITS);
            int p = atomicAdd(&cur[s], 1);
            buf[p] = pv[k];
        }
    }
    __syncthreads();

    int total = start[ns];
    for (int j = t; j < total; j += PB) {
        int l = 0, h = ns;
        while (h - l > 1) { int mid = (l + h) >> 1; if (start[mid] <= j) l = mid; else h = mid; }
        int g = gbase[l] + (j - start[l]);
        if (g < (bin * NS_MAX + l) * CAP2 + CAP2) csrp[g] = buf[j];
    }

    // flush degree partial (u16, coalesced)
    unsigned short* dout = pdeg + ((size_t)bin * 16 + chunk) * RNGD;
    for (int i = t; i < RNGD; i += PB) dout[i] = (unsigned short)deg[i];
}

__global__ void k_mergedeg(const unsigned short* __restrict__ pdeg,
                           float* __restrict__ dinv, int n) {
    int i = blockIdx.x * blockDim.x + threadIdx.x;
    if (i >= n) return;
    int bin = i >> RBITS, local = i & (RNGD - 1);
    const unsigned short* p = pdeg + (size_t)bin * 16 * RNGD + local;
    int s = 0;
#pragma unroll
    for (int k = 0; k < 16; k++) s += p[(size_t)k * RNGD];
    dinv[i] = rsqrtf(1.0f + (float)s);
}

// ---------------- layer 1 linear: g1 = dinv * (x @ W1), wave-per-row ----------------

__global__ void k_linear1(const float* __restrict__ x, const float* __restrict__ W1,
                          const float* __restrict__ dinv, float4* __restrict__ g1, int n) {
    int lane = threadIdx.x & 63;
    int wave = blockIdx.x * (blockDim.x >> 6) + (threadIdx.x >> 6);
    int nwaves = gridDim.x * (blockDim.x >> 6);
    float4 w0 = ((const float4*)W1)[2 * lane];
    float4 w1 = ((const float4*)W1)[2 * lane + 1];
    for (int row = wave; row < n; row += nwaves) {
        float2 xv = ((const float2*)(x + (size_t)row * 128))[lane];
        float p0 = xv.x * w0.x + xv.y * w1.x;
        float p1 = xv.x * w0.y + xv.y * w1.y;
        float p2 = xv.x * w0.z + xv.y * w1.z;
        float p3 = xv.x * w0.w + xv.y * w1.w;
#pragma unroll
        for (int off = 32; off; off >>= 1) {
            p0 += __shfl_xor(p0, off, 64);
            p1 += __shfl_xor(p1, off, 64);
            p2 += __shfl_xor(p2, off, 64);
            p3 += __shfl_xor(p3, off, 64);
        }
        if (lane == 0) {
            float dv = dinv[row];
            g1[row] = make_float4(dv * p0, dv * p1, dv * p2, dv * p3);
        }
    }
}

// ---------------- staged-window aggregation (no divergent global loads) ----------------

__global__ __launch_bounds__(PB) void k_bagg4s(const int* __restrict__ csrp,
                                               const int* __restrict__ c2,
                                               const float4* __restrict__ gin,
                                               float* __restrict__ partial,
                                               int ns, int n) {
    __shared__ float acc[RNGD * 4];   // 64KB
    __shared__ float4 win[SW];        // 16KB staged src window
    int t = threadIdx.x;
    int bin = blockIdx.x / SL, sl = blockIdx.x % SL;
    for (int i = t; i < RNGD * 4; i += PB) acc[i] = 0.0f;
    __syncthreads();
    int spb = (ns + SL - 1) / SL;
    int s0 = sl * spb, s1 = s0 + spb; if (s1 > ns) s1 = ns;
    for (int s = s0; s < s1; s++) {
        int gi = (s << SBITS) + t;                 // PB == SW: one node per thread
        win[t] = (gi < n) ? gin[gi] : make_float4(0.f, 0.f, 0.f, 0.f);
        __syncthreads();
        int b2 = (bin * NS_MAX + s) * CAP2;
        int e2 = c2[(bin * NS_MAX + s) * 16]; if (e2 > b2 + CAP2) e2 = b2 + CAP2;
        for (int j = b2 + t; j < e2; j += PB) {
            int p = __builtin_nontemporal_load(csrp + j);
            int local = p & (RNGD - 1);
            float4 g = win[(p >> RBITS) & (SW - 1)];
            int sw = (local >> 3) & 3;
            atomicAdd(&acc[local * 4 + (0 ^ sw)], g.x);
            atomicAdd(&acc[local * 4 + (1 ^ sw)], g.y);
            atomicAdd(&acc[local * 4 + (2 ^ sw)], g.z);
            atomicAdd(&acc[local * 4 + (3 ^ sw)], g.w);
        }
        __syncthreads();
    }
    float* out = partial + (size_t)blockIdx.x * (RNGD * 4);
    for (int i = t; i < RNGD * 4; i += PB) out[i] = acc[i];
}

__global__ __launch_bounds__(PB) void k_bagg2s(const int* __restrict__ csrp,
                                               const int* __restrict__ c2,
                                               const float2* __restrict__ gin,
                                               float* __restrict__ partial,
                                               int ns, int n) {
    __shared__ float acc[RNGD * 2];   // 32KB
    __shared__ float2 win[SW];        // 8KB
    int t = threadIdx.x;
    int bin = blockIdx.x / SL, sl = blockIdx.x % SL;
    for (int i = t; i < RNGD * 2; i += PB) acc[i] = 0.0f;
    __syncthreads();
    int spb = (ns + SL - 1) / SL;
    int s0 = sl * spb, s1 = s0 + spb; if (s1 > ns) s1 = ns;
    for (int s = s0; s < s1; s++) {
        int gi = (s << SBITS) + t;
        win[t] = (gi < n) ? gin[gi] : make_float2(0.f, 0.f);
        __syncthreads();
        int b2 = (bin * NS_MAX + s) * CAP2;
        int e2 = c2[(bin * NS_MAX + s) * 16]; if (e2 > b2 + CAP2) e2 = b2 + CAP2;
        for (int j = b2 + t; j < e2; j += PB) {
            int p = __builtin_nontemporal_load(csrp + j);
            int local = p & (RNGD - 1);
            float2 g = win[(p >> RBITS) & (SW - 1)];
            int sw = (local >> 4) & 1;
            atomicAdd(&acc[local * 2 + (0 ^ sw)], g.x);
            atomicAdd(&acc[local * 2 + (1 ^ sw)], g.y);
        }
        __syncthreads();
    }
    float* out = partial + (size_t)blockIdx.x * (RNGD * 2);
    for (int i = t; i < RNGD * 2; i += PB) out[i] = acc[i];
}

// ---------------- merges (partial-sum + self term + tanh + next linear) ----------------

__global__ void k_merge44(const float* __restrict__ partial, const float4* __restrict__ gin,
                          const float* __restrict__ dinv, float4* __restrict__ gout,
                          const float* __restrict__ W, const float* __restrict__ bv, int n) {
    int i = blockIdx.x * blockDim.x + threadIdx.x;
    if (i >= n) return;
    int bin = i >> RBITS, local = i & (RNGD - 1);
    const float4* p = (const float4*)partial + (size_t)bin * SL * RNGD + local;
    float a[4] = {0.f, 0.f, 0.f, 0.f};
#pragma unroll
    for (int k = 0; k < SL; k++) {
        float4 v = p[(size_t)k * RNGD];
        a[0] += v.x; a[1] += v.y; a[2] += v.z; a[3] += v.w;
    }
    int sw = (local >> 3) & 3;
    float f0 = a[0 ^ sw], f1 = a[1 ^ sw], f2 = a[2 ^ sw], f3 = a[3 ^ sw];
    float4 gs = gin[i];
    float dv = dinv[i];
    float t0 = tanhf(dv * (gs.x + f0) + bv[0]);
    float t1 = tanhf(dv * (gs.y + f1) + bv[1]);
    float t2 = tanhf(dv * (gs.z + f2) + bv[2]);
    float t3 = tanhf(dv * (gs.w + f3) + bv[3]);
    float4 o;
    o.x = dv * (t0 * W[0] + t1 * W[4] + t2 * W[8]  + t3 * W[12]);
    o.y = dv * (t0 * W[1] + t1 * W[5] + t2 * W[9]  + t3 * W[13]);
    o.z = dv * (t0 * W[2] + t1 * W[6] + t2 * W[10] + t3 * W[14]);
    o.w = dv * (t0 * W[3] + t1 * W[7] + t2 * W[11] + t3 * W[15]);
    gout[i] = o;
}

__global__ void k_merge42(const float* __restrict__ partial, const float4* __restrict__ gin,
                          const float* __restrict__ dinv, float2* __restrict__ gout,
                          const float* __restrict__ W, const float* __restrict__ bv, int n) {
    int i = blockIdx.x * blockDim.x + threadIdx.x;
    if (i >= n) return;
    int bin = i >> RBITS, local = i & (RNGD - 1);
    const float4* p = (const float4*)partial + (size_t)bin * SL * RNGD + local;
    float a[4] = {0.f, 0.f, 0.f, 0.f};
#pragma unroll
    for (int k = 0; k < SL; k++) {
        float4 v = p[(size_t)k * RNGD];
        a[0] += v.x; a[1] += v.y; a[2] += v.z; a[3] += v.w;
    }
    int sw = (local >> 3) & 3;
    float f0 = a[0 ^ sw], f1 = a[1 ^ sw], f2 = a[2 ^ sw], f3 = a[3 ^ sw];
    float4 gs = gin[i];
    float dv = dinv[i];
    float t0 = tanhf(dv * (gs.x + f0) + bv[0]);
    float t1 = tanhf(dv * (gs.y + f1) + bv[1]);
    float t2 = tanhf(dv * (gs.z + f2) + bv[2]);
    float t3 = tanhf(dv * (gs.w + f3) + bv[3]);
    float h0 = t0 * W[0] + t1 * W[2] + t2 * W[4] + t3 * W[6];
    float h1 = t0 * W[1] + t1 * W[3] + t2 * W[5] + t3 * W[7];
    gout[i] = make_float2(dv * h0, dv * h1);
}

__global__ void k_merge2out(const float* __restrict__ partial, const float2* __restrict__ gin,
                            const float* __restrict__ dinv, const float* __restrict__ b3,
                            const float* __restrict__ Wc, const float* __restrict__ bc,
                            float* __restrict__ out, float2* __restrict__ hout, int n) {
    int i = blockIdx.x * blockDim.x + threadIdx.x;
    if (i >= n) return;
    int bin = i >> RBITS, local = i & (RNGD - 1);
    const float2* p = (const float2*)partial + (size_t)bin * SL * RNGD + local;
    float a[2] = {0.f, 0.f};
#pragma unroll
    for (int k = 0; k < SL; k++) {
        float2 v = p[(size_t)k * RNGD];
        a[0] += v.x; a[1] += v.y;
    }
    int sw = (local >> 4) & 1;
    float f0 = a[0 ^ sw], f1 = a[1 ^ sw];
    float2 gs = gin[i];
    float dv = dinv[i];
    float t0 = tanhf(dv * (gs.x + f0) + b3[0]);
    float t1 = tanhf(dv * (gs.y + f1) + b3[1]);
    hout[i] = make_float2(t0, t1);
    float4* o = (float4*)(out + (size_t)i * 16);
#pragma unroll
    for (int q = 0; q < 4; q++) {
        float4 v;
        v.x = t0 * Wc[4*q+0] + t1 * Wc[16+4*q+0] + bc[4*q+0];
        v.y = t0 * Wc[4*q+1] + t1 * Wc[16+4*q+1] + bc[4*q+1];
        v.z = t0 * Wc[4*q+2] + t1 * Wc[16+4*q+2] + bc[4*q+2];
        v.w = t0 * Wc[4*q+3] + t1 * Wc[16+4*q+3] + bc[4*q+3];
        o[q] = v;
    }
}

// ---------------- fallback path: round-5 proven 1-D bucketed version ----------------

#define FNR 500
#define FRNG 400
#define FCAP 16384
#define FHB 1024
#define FEPT 8
#define FEPB (FHB * FEPT)
#define FAB 1024

__global__ void kf_initcur(int* __restrict__ cursor) {
    int t = blockIdx.x * blockDim.x + threadIdx.x;
    if (t < FNR) cursor[t * 16] = t * FCAP;
}

__global__ __launch_bounds__(FHB) void kf_build(const int* __restrict__ src,
                                                const int* __restrict__ dst,
                                                int* __restrict__ cursor,
                                                int* __restrict__ csrp, int e) {
    __shared__ int hist[FNR];
    __shared__ int scn[FHB];
    __shared__ int start[FNR + 1];
    __shared__ int gbase[FNR];
    __shared__ int cur[FNR];
    __shared__ int buf[FEPB];
    int t = threadIdx.x;
    for (int i = t; i < FNR; i += FHB) hist[i] = 0;
    __syncthreads();
    int ds[FEPT], sr[FEPT];
    int base = blockIdx.x * FEPB;
#pragma unroll
    for (int k = 0; k < 2; k++) {
        int idx = base + k * FHB * 4 + t * 4;
        if (idx + 3 < e) {
            int4 d4 = *(const int4*)(dst + idx);
            int4 s4 = *(const int4*)(src + idx);
            ds[4*k+0]=d4.x; ds[4*k+1]=d4.y; ds[4*k+2]=d4.z; ds[4*k+3]=d4.w;
            sr[4*k+0]=s4.x; sr[4*k+1]=s4.y; sr[4*k+2]=s4.z; sr[4*k+3]=s4.w;
        } else {
#pragma unroll
            for (int j = 0; j < 4; j++) {
                int i2 = idx + j;
                if (i2 < e) { ds[4*k+j] = dst[i2]; sr[4*k+j] = src[i2]; }
                else ds[4*k+j] = -1;
            }
        }
    }
#pragma unroll
    for (int k = 0; k < FEPT; k++)
        if (ds[k] >= 0) atomicAdd(&hist[ds[k] / FRNG], 1);
    __syncthreads();
    scn[t] = (t < FNR) ? hist[t] : 0;
    __syncthreads();
    for (int off = 1; off < FHB; off <<= 1) {
        int add = (t >= off) ? scn[t - off] : 0;
        __syncthreads();
        scn[t] += add;
        __syncthreads();
    }
    if (t < FNR) {
        int c = hist[t];
        int st = scn[t] - c;
        start[t] = st; cur[t] = st;
        gbase[t] = c ? atomicAdd(&cursor[t * 16], c) : 0;
    }
    if (t == 0) start[FNR] = scn[FNR - 1];
    __syncthreads();
#pragma unroll
    for (int k = 0; k < FEPT; k++) {
        if (ds[k] >= 0) {
            int bin = ds[k] / FRNG;
            int p = atomicAdd(&cur[bin], 1);
            buf[p] = (sr[k] << 9) | (ds[k] - bin * FRNG);
        }
    }
    __syncthreads();
    int total = start[FNR];
    for (int j = t; j < total; j += FHB) {
        int lo = 0, hi = FNR;
        while (hi - lo > 1) { int mid = (lo + hi) >> 1; if (start[mid] <= j) lo = mid; else hi = mid; }
        int g = gbase[lo] + (j - start[lo]);
        if (g < (lo + 1) * FCAP) csrp[g] = buf[j];
    }
}

__global__ __launch_bounds__(FAB) void kf_bdeg(const int* __restrict__ csrp,
                                               const int* __restrict__ cursor,
                                               float* __restrict__ dinv, int n) {
    __shared__ int deg[FRNG];
    int t = threadIdx.x, b = blockIdx.x;
    for (int i = t; i < FRNG; i += FAB) deg[i] = 0;
    __syncthreads();
    int s0 = b * FCAP;
    int s1 = cursor[b * 16]; if (s1 > s0 + FCAP) s1 = s0 + FCAP;
    int cnt = s1 - s0;
    const int4* cp = (const int4*)(csrp + s0);
    int ng = cnt >> 2;
    for (int g = t; g < ng; g += FAB) {
        int4 p = cp[g];
        atomicAdd(&deg[p.x & 511], 1);
        atomicAdd(&deg[p.y & 511], 1);
        atomicAdd(&deg[p.z & 511], 1);
        atomicAdd(&deg[p.w & 511], 1);
    }
    int rem = s0 + (ng << 2) + t;
    if (rem < s1) atomicAdd(&deg[csrp[rem] & 511], 1);
    __syncthreads();
    int basen = b * FRNG;
    for (int i = t; i < FRNG; i += FAB) {
        int node = basen + i;
        if (node < n) dinv[node] = rsqrtf(1.0f + (float)deg[i]);
    }
}

__device__ __forceinline__ void facc4(float* acc, int p, const float4* __restrict__ gin) {
    int local = p & 511;
    float4 g = gin[p >> 9];
    atomicAdd(&acc[local * 5 + 0], g.x);
    atomicAdd(&acc[local * 5 + 1], g.y);
    atomicAdd(&acc[local * 5 + 2], g.z);
    atomicAdd(&acc[local * 5 + 3], g.w);
}

__global__ __launch_bounds__(FAB) void kf_bagg44(const int* __restrict__ csrp,
                                                 const int* __restrict__ cursor,
                                                 const float* __restrict__ dinv,
                                                 const float4* __restrict__ gin,
                                                 float4* __restrict__ gout,
                                                 const float* __restrict__ W,
                                                 const float* __restrict__ bv, int n) {
    __shared__ float acc[FRNG * 5];
    int t = threadIdx.x, b = blockIdx.x;
    for (int i = t; i < FRNG * 5; i += FAB) acc[i] = 0.0f;
    __syncthreads();
    int s0 = b * FCAP;
    int s1 = cursor[b * 16]; if (s1 > s0 + FCAP) s1 = s0 + FCAP;
    int cnt = s1 - s0;
    const int4* cp = (const int4*)(csrp + s0);
    int ng = cnt >> 2;
    for (int g = t; g < ng; g += FAB) {
        int4 p = cp[g];
        facc4(acc, p.x, gin); facc4(acc, p.y, gin);
        facc4(acc, p.z, gin); facc4(acc, p.w, gin);
    }
    int rem = s0 + (ng << 2) + t;
    if (rem < s1) facc4(acc, csrp[rem], gin);
    __syncthreads();
    int basen = b * FRNG;
    for (int i = t; i < FRNG; i += FAB) {
        int node = basen + i;
        if (node >= n) continue;
        float4 gs = gin[node];
        float dv = dinv[node];
        float t0 = tanhf(dv * (gs.x + acc[i*5+0]) + bv[0]);
        float t1 = tanhf(dv * (gs.y + acc[i*5+1]) + bv[1]);
        float t2 = tanhf(dv * (gs.z + acc[i*5+2]) + bv[2]);
        float t3 = tanhf(dv * (gs.w + acc[i*5+3]) + bv[3]);
        float4 o;
        o.x = dv * (t0*W[0] + t1*W[4] + t2*W[8]  + t3*W[12]);
        o.y = dv * (t0*W[1] + t1*W[5] + t2*W[9]  + t3*W[13]);
        o.z = dv * (t0*W[2] + t1*W[6] + t2*W[10] + t3*W[14]);
        o.w = dv * (t0*W[3] + t1*W[7] + t2*W[11] + t3*W[15]);
        gout[node] = o;
    }
}

__global__ __launch_bounds__(FAB) void kf_bagg42(const int* __restrict__ csrp,
                                                 const int* __restrict__ cursor,
                                                 const float* __restrict__ dinv,
                                                 const float4* __restrict__ gin,
                                                 float2* __restrict__ gout,
                                                 const float* __restrict__ W,
                                                 const float* __restrict__ bv, int n) {
    __shared__ float acc[FRNG * 5];
    int t = threadIdx.x, b = blockIdx.x;
    for (int i = t; i < FRNG * 5; i += FAB) acc[i] = 0.0f;
    __syncthreads();
    int s0 = b * FCAP;
    int s1 = cursor[b * 16]; if (s1 > s0 + FCAP) s1 = s0 + FCAP;
    int cnt = s1 - s0;
    const int4* cp = (const int4*)(csrp + s0);
    int ng = cnt >> 2;
    for (int g = t; g < ng; g += FAB) {
        int4 p = cp[g];
        facc4(acc, p.x, gin); facc4(acc, p.y, gin);
        facc4(acc, p.z, gin); facc4(acc, p.w, gin);
    }
    int rem = s0 + (ng << 2) + t;
    if (rem < s1) facc4(acc, csrp[rem], gin);
    __syncthreads();
    int basen = b * FRNG;
    for (int i = t; i < FRNG; i += FAB) {
        int node = basen + i;
        if (node >= n) continue;
        float4 gs = gin[node];
        float dv = dinv[node];
        float t0 = tanhf(dv * (gs.x + acc[i*5+0]) + bv[0]);
        float t1 = tanhf(dv * (gs.y + acc[i*5+1]) + bv[1]);
        float t2 = tanhf(dv * (gs.z + acc[i*5+2]) + bv[2]);
        float t3 = tanhf(dv * (gs.w + acc[i*5+3]) + bv[3]);
        float h0 = t0*W[0] + t1*W[2] + t2*W[4] + t3*W[6];
        float h1 = t0*W[1] + t1*W[3] + t2*W[5] + t3*W[7];
        gout[node] = make_float2(dv * h0, dv * h1);
    }
}

__global__ __launch_bounds__(FAB) void kf_bagg2out(const int* __restrict__ csrp,
                                                   const int* __restrict__ cursor,
                                                   const float* __restrict__ dinv,
                                                   const float2* __restrict__ gin,
                                                   const float* __restrict__ b3,
                                                   const float* __restrict__ Wc,
                                                   const float* __restrict__ bc,
                                                   float* __restrict__ out,
                                                   float2* __restrict__ hout, int n) {
    __shared__ float acc[FRNG * 3];
    int t = threadIdx.x, b = blockIdx.x;
    for (int i = t; i < FRNG * 3; i += FAB) acc[i] = 0.0f;
    __syncthreads();
    int s0 = b * FCAP;
    int s1 = cursor[b * 16]; if (s1 > s0 + FCAP) s1 = s0 + FCAP;
    int cnt = s1 - s0;
    const int4* cp = (const int4*)(csrp + s0);
    int ng = cnt >> 2;
    for (int g = t; g < ng; g += FAB) {
        int4 p = cp[g];
#pragma unroll
        for (int q = 0; q < 4; q++) {
            int pv = (q == 0) ? p.x : (q == 1) ? p.y : (q == 2) ? p.z : p.w;
            float2 gv = gin[pv >> 9];
            int local = pv & 511;
            atomicAdd(&acc[local * 3 + 0], gv.x);
            atomicAdd(&acc[local * 3 + 1], gv.y);
        }
    }
    int rem = s0 + (ng << 2) + t;
    if (rem < s1) {
        int pv = csrp[rem];
        float2 gv = gin[pv >> 9];
        int local = pv & 511;
        atomicAdd(&acc[local * 3 + 0], gv.x);
        atomicAdd(&acc[local * 3 + 1], gv.y);
    }
    __syncthreads();
    int basen = b * FRNG;
    for (int i = t; i < FRNG; i += FAB) {
        int node = basen + i;
        if (node >= n) continue;
        float2 gs = gin[node];
        float dv = dinv[node];
        float t0 = tanhf(dv * (gs.x + acc[i*3+0]) + b3[0]);
        float t1 = tanhf(dv * (gs.y + acc[i*3+1]) + b3[1]);
        hout[node] = make_float2(t0, t1);
        float4* o = (float4*)(out + (size_t)node * 16);
#pragma unroll
        for (int q = 0; q < 4; q++) {
            float4 v;
            v.x = t0*Wc[4*q+0] + t1*Wc[16+4*q+0] + bc[4*q+0];
            v.y = t0*Wc[4*q+1] + t1*Wc[16+4*q+1] + bc[4*q+1];
            v.z = t0*Wc[4*q+2] + t1*Wc[16+4*q+2] + bc[4*q+2];
            v.w = t0*Wc[4*q+3] + t1*Wc[16+4*q+3] + bc[4*q+3];
            o[q] = v;
        }
    }
}

// ---------------- launcher ----------------

extern "C" void kernel_launch(void* const* d_in, const int* in_sizes, int n_in,
                              void* d_out, int out_size, void* d_ws, size_t ws_size,
                              hipStream_t stream) {
    const float* x   = (const float*)d_in[0];
    const float* W1  = (const float*)d_in[1];
    const float* b1  = (const float*)d_in[2];
    const float* W2  = (const float*)d_in[3];
    const float* b2  = (const float*)d_in[4];
    const float* W3  = (const float*)d_in[5];
    const float* b3  = (const float*)d_in[6];
    const float* Wc  = (const float*)d_in[7];
    const float* bc  = (const float*)d_in[8];
    const int* eidx  = (const int*)d_in[9];

    const int n = in_sizes[0] / 128;   // 200000
    const int e = in_sizes[9] / 2;     // 6400000
    const int* src = eidx;
    const int* dst = eidx + e;

    float* out_c = (float*)d_out;                   // [n,16]
    float* out_h = (float*)d_out + 16 * (size_t)n;  // [n,2]

    size_t nP = ((size_t)n + 3) & ~(size_t)3;

    // 2-D fast-path workspace layout.
    // regA holds: [buf1 (26.1MB) | pdeg u16 (6.4MB)] during build,
    //             then partials (32.1MB) during aggregation (disjoint lifetimes).
    size_t buf1_elems   = (size_t)NRD_MAX * CAP1;                 // ints
    size_t pdeg_elems_i = ((size_t)NRD_MAX * 16 * RNGD + 1) / 2;  // u16 in int units
    size_t part_elems   = (size_t)NRD_MAX * SL * RNGD * 4;        // floats
    size_t szA = buf1_elems + pdeg_elems_i;
    if (part_elems > szA) szA = part_elems;

    int* regA    = (int*)d_ws;
    int* csrp2   = regA + szA;
    int* cur1    = csrp2 + (size_t)NRD_MAX * NS_MAX * CAP2;
    int* cur2    = cur1 + NRD_MAX * 16;
    float* dinv2 = (float*)(cur2 + NRD_MAX * NS_MAX * 16);
    float* g1    = dinv2 + nP;
    float* g2    = g1 + 4 * nP;
    float* g3    = g2 + 4 * nP;
    size_t need2 = (size_t)((char*)(g3 + 2 * nP) - (char*)d_ws);

    int nrd = (n + RNGD - 1) >> RBITS;
    int ns  = (n + SW - 1) >> SBITS;
    bool ok_cap1 = (long long)e * RNGD <= (long long)(CAP1 - 2048) * n;
    double mean2 = (double)e * RNGD * SW / ((double)n * (double)n);
    bool ok_cap2 = mean2 <= (double)(CAP2 - 192);
    bool fast2 = (ws_size >= need2) && (n <= NRD_MAX * RNGD) && (n >= (1 << 15)) &&
                 ok_cap1 && ok_cap2 && (n < (1 << 18));

    if (fast2) {
        int* buf1 = regA;                                         // build phase
        unsigned short* pdeg = (unsigned short*)(regA + buf1_elems);
        float* part = (float*)regA;                               // agg phase

        k_initcur2d<<<(NRD_MAX * NS_MAX + 255) / 256, 256, 0, stream>>>(cur1, cur2);
        k_pass1<<<(e + EPB1 - 1) / EPB1, PB, 0, stream>>>(src, dst, cur1, buf1, e, nrd);
        k_pass2<<<nrd * 16, PB, 0, stream>>>(buf1, cur1, cur2, csrp2, pdeg, ns);
        k_mergedeg<<<(n + 255) / 256, 256, 0, stream>>>(pdeg, dinv2, n);
        k_linear1<<<(n + 3) / 4, 256, 0, stream>>>(x, W1, dinv2, (float4*)g1, n);
        k_bagg4s<<<nrd * SL, PB, 0, stream>>>(csrp2, cur2, (const float4*)g1, part, ns, n);
        k_merge44<<<(n + 255) / 256, 256, 0, stream>>>(part, (const float4*)g1, dinv2,
                                                       (float4*)g2, W2, b1, n);
        k_bagg4s<<<nrd * SL, PB, 0, stream>>>(csrp2, cur2, (const float4*)g2, part, ns, n);
        k_merge42<<<(n + 255) / 256, 256, 0, stream>>>(part, (const float4*)g2, dinv2,
                                                       (float2*)g3, W3, b2, n);
        k_bagg2s<<<nrd * SL, PB, 0, stream>>>(csrp2, cur2, (const float2*)g3, part, ns, n);
        k_merge2out<<<(n + 255) / 256, 256, 0, stream>>>(part, (const float2*)g3, dinv2,
                                                         b3, Wc, bc, out_c, (float2*)out_h, n);
    } else {
        // fallback: round-5 proven 1-D path (~46MB ws)
        int* csrp    = (int*)d_ws;
        int* cursor  = csrp + (size_t)FNR * FCAP;
        float* dinv  = (float*)(cursor + FNR * 16);
        float* fg1   = dinv + nP;
        float* fg2   = fg1 + 4 * nP;
        float* fg3   = fg2 + 4 * nP;

        const int nbE = (e + FEPB - 1) / FEPB;
        kf_initcur<<<(FNR + 255) / 256, 256, 0, stream>>>(cursor);
        kf_build<<<nbE, FHB, 0, stream>>>(src, dst, cursor, csrp, e);
        kf_bdeg<<<FNR, FAB, 0, stream>>>(csrp, cursor, dinv, n);
        k_linear1<<<(n + 3) / 4, 256, 0, stream>>>(x, W1, dinv, (float4*)fg1, n);
        kf_bagg44<<<FNR, FAB, 0, stream>>>(csrp, cursor, dinv, (const float4*)fg1,
                                           (float4*)fg2, W2, b1, n);
        kf_bagg42<<<FNR, FAB, 0, stream>>>(csrp, cursor, dinv, (const float4*)fg2,
                                           (float2*)fg3, W3, b2, n);
        kf_bagg2out<<<FNR, FAB, 0, stream>>>(csrp, cursor, dinv, (const float2*)fg3,
                                             b3, Wc, bc, out_c, (float2*)out_h, n);
    }
}

// Round 8
// 619.557 us; speedup vs baseline: 1.1879x; 1.1879x over previous
//
#include <hip/hip_runtime.h>
#include <math.h>

// GCN 3-layer + classifier — round-5 1-D bucketed structure + round-8 MLP fix.
//
// Rounds 1-7 law: every edge-pass kernel cost ~130-170us with ALL pipes idle
// (VALUBusy 1-4%, HBM 3-5%, VGPR_Count=8). Diagnosis: zero memory-level
// parallelism — each wave serializes one ~400cy memory round-trip per edge;
// 800 edges/wave x 400cy = 133us wall regardless of occupancy or gather
// locality (which is why rounds 5/6/7 all failed to move it).
// Round 8: batch 8 edges/lane/iteration — 2 coalesced int4 edge-pack loads,
// 8 gathers issued into registers before any use, then 32 LDS atomics.
// Chain: ~160 serial round-trips -> ~2.
//
// Math identity: agg[d] = dinv[d]*( g[d] + sum_{in} g[s] ),  g = dinv*h.

#define NR 500
#define RNG 400
#define CAP 16384            // slots per bin (expect ~12800 +- 113)
#define HB 1024              // build threads
#define EPT 8                // edges per thread (registers)
#define EPB (HB * EPT)       // 8192 edges per block
#define AB 1024              // aggregation threads per block

// ---------------- build ----------------

__global__ void k_initcur(int* __restrict__ cursor) {
    int t = blockIdx.x * blockDim.x + threadIdx.x;
    if (t < NR) cursor[t * 16] = t * CAP;
}

__global__ __launch_bounds__(HB) void k_build(const int* __restrict__ src,
                                              const int* __restrict__ dst,
                                              int* __restrict__ cursor,
                                              int* __restrict__ csrp, int e) {
    __shared__ int hist[NR];
    __shared__ int scn[HB];
    __shared__ int start[NR + 1];
    __shared__ int gbase[NR];
    __shared__ int cur[NR];
    __shared__ int buf[EPB];

    int t = threadIdx.x;
    for (int i = t; i < NR; i += HB) hist[i] = 0;
    __syncthreads();

    int ds[EPT], sr[EPT];
    int base = blockIdx.x * EPB;
#pragma unroll
    for (int k = 0; k < 2; k++) {
        int idx = base + k * HB * 4 + t * 4;
        if (idx + 3 < e) {
            int4 d4 = *(const int4*)(dst + idx);
            int4 s4 = *(const int4*)(src + idx);
            ds[4 * k + 0] = d4.x; ds[4 * k + 1] = d4.y; ds[4 * k + 2] = d4.z; ds[4 * k + 3] = d4.w;
            sr[4 * k + 0] = s4.x; sr[4 * k + 1] = s4.y; sr[4 * k + 2] = s4.z; sr[4 * k + 3] = s4.w;
        } else {
#pragma unroll
            for (int j = 0; j < 4; j++) {
                int i2 = idx + j;
                if (i2 < e) { ds[4 * k + j] = dst[i2]; sr[4 * k + j] = src[i2]; }
                else ds[4 * k + j] = -1;
            }
        }
    }
#pragma unroll
    for (int k = 0; k < EPT; k++)
        if (ds[k] >= 0) atomicAdd(&hist[ds[k] / RNG], 1);
    __syncthreads();

    scn[t] = (t < NR) ? hist[t] : 0;
    __syncthreads();
    for (int off = 1; off < HB; off <<= 1) {
        int add = (t >= off) ? scn[t - off] : 0;
        __syncthreads();
        scn[t] += add;
        __syncthreads();
    }
    if (t < NR) {
        int c = hist[t];
        int st = scn[t] - c;
        start[t] = st;
        cur[t] = st;
        gbase[t] = c ? atomicAdd(&cursor[t * 16], c) : 0;
    }
    if (t == 0) start[NR] = scn[NR - 1];
    __syncthreads();

#pragma unroll
    for (int k = 0; k < EPT; k++) {
        if (ds[k] >= 0) {
            int bin = ds[k] / RNG;
            int p = atomicAdd(&cur[bin], 1);
            buf[p] = (sr[k] << 9) | (ds[k] - bin * RNG);
        }
    }
    __syncthreads();

    int total = start[NR];
    for (int j = t; j < total; j += HB) {
        int lo = 0, hi = NR;
        while (hi - lo > 1) {
            int mid = (lo + hi) >> 1;
            if (start[mid] <= j) lo = mid; else hi = mid;
        }
        int g = gbase[lo] + (j - start[lo]);
        if (g < (lo + 1) * CAP) csrp[g] = buf[j];
    }
}

// ---------------- degree (bucketed, LDS, 4-stream batched reads) ----------------

__global__ __launch_bounds__(AB) void k_bdeg(const int* __restrict__ csrp,
                                             const int* __restrict__ cursor,
                                             float* __restrict__ dinv, int n) {
    __shared__ int deg[RNG];
    int t = threadIdx.x, b = blockIdx.x;
    for (int i = t; i < RNG; i += AB) deg[i] = 0;
    __syncthreads();
    int s0 = b * CAP;
    int s1 = cursor[b * 16]; if (s1 > s0 + CAP) s1 = s0 + CAP;
    int cnt = s1 - s0; if (cnt < 0) cnt = 0;
    const int4* cp = (const int4*)(csrp + s0);
    int nI = cnt >> 2;
    int q = nI >> 2;                   // quads of int4 = 16 edges per iter
    for (int i = t; i < q; i += AB) {
        int4 a = cp[i];
        int4 b4 = cp[i + q];
        int4 c4 = cp[i + 2 * q];
        int4 d4 = cp[i + 3 * q];
        atomicAdd(&deg[a.x & 511], 1);  atomicAdd(&deg[a.y & 511], 1);
        atomicAdd(&deg[a.z & 511], 1);  atomicAdd(&deg[a.w & 511], 1);
        atomicAdd(&deg[b4.x & 511], 1); atomicAdd(&deg[b4.y & 511], 1);
        atomicAdd(&deg[b4.z & 511], 1); atomicAdd(&deg[b4.w & 511], 1);
        atomicAdd(&deg[c4.x & 511], 1); atomicAdd(&deg[c4.y & 511], 1);
        atomicAdd(&deg[c4.z & 511], 1); atomicAdd(&deg[c4.w & 511], 1);
        atomicAdd(&deg[d4.x & 511], 1); atomicAdd(&deg[d4.y & 511], 1);
        atomicAdd(&deg[d4.z & 511], 1); atomicAdd(&deg[d4.w & 511], 1);
    }
    for (int j = s0 + 16 * q + t; j < s1; j += AB)
        atomicAdd(&deg[csrp[j] & 511], 1);
    __syncthreads();
    int basen = b * RNG;
    for (int i = t; i < RNG; i += AB) {
        int node = basen + i;
        if (node < n) dinv[node] = rsqrtf(1.0f + (float)deg[i]);
    }
}

// ---------------- layer 1 linear: g1 = dinv * (x @ W1), wave-per-row ----------------

__global__ void k_linear1(const float* __restrict__ x, const float* __restrict__ W1,
                          const float* __restrict__ dinv, float4* __restrict__ g1, int n) {
    int lane = threadIdx.x & 63;
    int wave = blockIdx.x * (blockDim.x >> 6) + (threadIdx.x >> 6);
    int nwaves = gridDim.x * (blockDim.x >> 6);

    float4 w0 = ((const float4*)W1)[2 * lane];
    float4 w1 = ((const float4*)W1)[2 * lane + 1];

    for (int row = wave; row < n; row += nwaves) {
        float2 xv = ((const float2*)(x + (size_t)row * 128))[lane];
        float p0 = xv.x * w0.x + xv.y * w1.x;
        float p1 = xv.x * w0.y + xv.y * w1.y;
        float p2 = xv.x * w0.z + xv.y * w1.z;
        float p3 = xv.x * w0.w + xv.y * w1.w;
#pragma unroll
        for (int off = 32; off; off >>= 1) {
            p0 += __shfl_xor(p0, off, 64);
            p1 += __shfl_xor(p1, off, 64);
            p2 += __shfl_xor(p2, off, 64);
            p3 += __shfl_xor(p3, off, 64);
        }
        if (lane == 0) {
            float dv = dinv[row];
            g1[row] = make_float4(dv * p0, dv * p1, dv * p2, dv * p3);
        }
    }
}

// ---------------- MLP-batched bucketed aggregation ----------------

__device__ __forceinline__ void lds4(float* acc, int p, float4 g) {
    int local = p & 511;
    atomicAdd(&acc[local * 5 + 0], g.x);
    atomicAdd(&acc[local * 5 + 1], g.y);
    atomicAdd(&acc[local * 5 + 2], g.z);
    atomicAdd(&acc[local * 5 + 3], g.w);
}

__device__ __forceinline__ void facc4(float* acc, int p, const float4* __restrict__ gin) {
    lds4(acc, p, gin[p >> 9]);
}

__global__ __launch_bounds__(AB) void k_bagg44(const int* __restrict__ csrp,
                                               const int* __restrict__ cursor,
                                               const float* __restrict__ dinv,
                                               const float4* __restrict__ gin,
                                               float4* __restrict__ gout,
                                               const float* __restrict__ W,
                                               const float* __restrict__ bv, int n) {
    __shared__ float acc[RNG * 5];
    int t = threadIdx.x, b = blockIdx.x;
    for (int i = t; i < RNG * 5; i += AB) acc[i] = 0.0f;
    __syncthreads();
    int s0 = b * CAP;
    int s1 = cursor[b * 16]; if (s1 > s0 + CAP) s1 = s0 + CAP;
    int cnt = s1 - s0; if (cnt < 0) cnt = 0;
    const int4* cp = (const int4*)(csrp + s0);
    int nI = cnt >> 2;
    int nPr = nI >> 1;                 // pairs of int4 = 8 edges per iter
    for (int i = t; i < nPr; i += AB) {
        int4 pa = cp[i];
        int4 pb = cp[i + nPr];
        float4 g0 = gin[pa.x >> 9];
        float4 g1 = gin[pa.y >> 9];
        float4 g2 = gin[pa.z >> 9];
        float4 g3 = gin[pa.w >> 9];
        float4 g4 = gin[pb.x >> 9];
        float4 g5 = gin[pb.y >> 9];
        float4 g6 = gin[pb.z >> 9];
        float4 g7 = gin[pb.w >> 9];
        lds4(acc, pa.x, g0); lds4(acc, pa.y, g1);
        lds4(acc, pa.z, g2); lds4(acc, pa.w, g3);
        lds4(acc, pb.x, g4); lds4(acc, pb.y, g5);
        lds4(acc, pb.z, g6); lds4(acc, pb.w, g7);
    }
    for (int j = s0 + (nPr << 3) + t; j < s1; j += AB)
        facc4(acc, csrp[j], gin);
    __syncthreads();
    int basen = b * RNG;
    for (int i = t; i < RNG; i += AB) {
        int node = basen + i;
        if (node >= n) continue;
        float4 gs = gin[node];
        float dv = dinv[node];
        float t0 = tanhf(dv * (gs.x + acc[i * 5 + 0]) + bv[0]);
        float t1 = tanhf(dv * (gs.y + acc[i * 5 + 1]) + bv[1]);
        float t2 = tanhf(dv * (gs.z + acc[i * 5 + 2]) + bv[2]);
        float t3 = tanhf(dv * (gs.w + acc[i * 5 + 3]) + bv[3]);
        float4 o;
        o.x = dv * (t0 * W[0] + t1 * W[4] + t2 * W[8]  + t3 * W[12]);
        o.y = dv * (t0 * W[1] + t1 * W[5] + t2 * W[9]  + t3 * W[13]);
        o.z = dv * (t0 * W[2] + t1 * W[6] + t2 * W[10] + t3 * W[14]);
        o.w = dv * (t0 * W[3] + t1 * W[7] + t2 * W[11] + t3 * W[15]);
        gout[node] = o;
    }
}

__global__ __launch_bounds__(AB) void k_bagg42(const int* __restrict__ csrp,
                                               const int* __restrict__ cursor,
                                               const float* __restrict__ dinv,
                                               const float4* __restrict__ gin,
                                               float2* __restrict__ gout,
                                               const float* __restrict__ W,
                                               const float* __restrict__ bv, int n) {
    __shared__ float acc[RNG * 5];
    int t = threadIdx.x, b = blockIdx.x;
    for (int i = t; i < RNG * 5; i += AB) acc[i] = 0.0f;
    __syncthreads();
    int s0 = b * CAP;
    int s1 = cursor[b * 16]; if (s1 > s0 + CAP) s1 = s0 + CAP;
    int cnt = s1 - s0; if (cnt < 0) cnt = 0;
    const int4* cp = (const int4*)(csrp + s0);
    int nI = cnt >> 2;
    int nPr = nI >> 1;
    for (int i = t; i < nPr; i += AB) {
        int4 pa = cp[i];
        int4 pb = cp[i + nPr];
        float4 g0 = gin[pa.x >> 9];
        float4 g1 = gin[pa.y >> 9];
        float4 g2 = gin[pa.z >> 9];
        float4 g3 = gin[pa.w >> 9];
        float4 g4 = gin[pb.x >> 9];
        float4 g5 = gin[pb.y >> 9];
        float4 g6 = gin[pb.z >> 9];
        float4 g7 = gin[pb.w >> 9];
        lds4(acc, pa.x, g0); lds4(acc, pa.y, g1);
        lds4(acc, pa.z, g2); lds4(acc, pa.w, g3);
        lds4(acc, pb.x, g4); lds4(acc, pb.y, g5);
        lds4(acc, pb.z, g6); lds4(acc, pb.w, g7);
    }
    for (int j = s0 + (nPr << 3) + t; j < s1; j += AB)
        facc4(acc, csrp[j], gin);
    __syncthreads();
    int basen = b * RNG;
    for (int i = t; i < RNG; i += AB) {
        int node = basen + i;
        if (node >= n) continue;
        float4 gs = gin[node];
        float dv = dinv[node];
        float t0 = tanhf(dv * (gs.x + acc[i * 5 + 0]) + bv[0]);
        float t1 = tanhf(dv * (gs.y + acc[i * 5 + 1]) + bv[1]);
        float t2 = tanhf(dv * (gs.z + acc[i * 5 + 2]) + bv[2]);
        float t3 = tanhf(dv * (gs.w + acc[i * 5 + 3]) + bv[3]);
        float h0 = t0 * W[0] + t1 * W[2] + t2 * W[4] + t3 * W[6];
        float h1 = t0 * W[1] + t1 * W[3] + t2 * W[5] + t3 * W[7];
        gout[node] = make_float2(dv * h0, dv * h1);
    }
}

__device__ __forceinline__ void lds2(float* acc, int p, float2 g) {
    int local = p & 511;
    atomicAdd(&acc[local * 3 + 0], g.x);
    atomicAdd(&acc[local * 3 + 1], g.y);
}

__global__ __launch_bounds__(AB) void k_bagg2out(const int* __restrict__ csrp,
                                                 const int* __restrict__ cursor,
                                                 const float* __restrict__ dinv,
                                                 const float2* __restrict__ gin,
                                                 const float* __restrict__ b3,
                                                 const float* __restrict__ Wc,
                                                 const float* __restrict__ bc,
                                                 float* __restrict__ out,
                                                 float2* __restrict__ hout, int n) {
    __shared__ float acc[RNG * 3];
    int t = threadIdx.x, b = blockIdx.x;
    for (int i = t; i < RNG * 3; i += AB) acc[i] = 0.0f;
    __syncthreads();
    int s0 = b * CAP;
    int s1 = cursor[b * 16]; if (s1 > s0 + CAP) s1 = s0 + CAP;
    int cnt = s1 - s0; if (cnt < 0) cnt = 0;
    const int4* cp = (const int4*)(csrp + s0);
    int nI = cnt >> 2;
    int nPr = nI >> 1;
    for (int i = t; i < nPr; i += AB) {
        int4 pa = cp[i];
        int4 pb = cp[i + nPr];
        float2 g0 = gin[pa.x >> 9];
        float2 g1 = gin[pa.y >> 9];
        float2 g2 = gin[pa.z >> 9];
        float2 g3 = gin[pa.w >> 9];
        float2 g4 = gin[pb.x >> 9];
        float2 g5 = gin[pb.y >> 9];
        float2 g6 = gin[pb.z >> 9];
        float2 g7 = gin[pb.w >> 9];
        lds2(acc, pa.x, g0); lds2(acc, pa.y, g1);
        lds2(acc, pa.z, g2); lds2(acc, pa.w, g3);
        lds2(acc, pb.x, g4); lds2(acc, pb.y, g5);
        lds2(acc, pb.z, g6); lds2(acc, pb.w, g7);
    }
    for (int j = s0 + (nPr << 3) + t; j < s1; j += AB) {
        int p = csrp[j];
        lds2(acc, p, gin[p >> 9]);
    }
    __syncthreads();
    int basen = b * RNG;
    for (int i = t; i < RNG; i += AB) {
        int node = basen + i;
        if (node >= n) continue;
        float2 gs = gin[node];
        float dv = dinv[node];
        float t0 = tanhf(dv * (gs.x + acc[i * 3 + 0]) + b3[0]);
        float t1 = tanhf(dv * (gs.y + acc[i * 3 + 1]) + b3[1]);
        hout[node] = make_float2(t0, t1);
        float4* o = (float4*)(out + (size_t)node * 16);
#pragma unroll
        for (int q = 0; q < 4; q++) {
            float4 v;
            v.x = t0 * Wc[4 * q + 0] + t1 * Wc[16 + 4 * q + 0] + bc[4 * q + 0];
            v.y = t0 * Wc[4 * q + 1] + t1 * Wc[16 + 4 * q + 1] + bc[4 * q + 1];
            v.z = t0 * Wc[4 * q + 2] + t1 * Wc[16 + 4 * q + 2] + bc[4 * q + 2];
            v.w = t0 * Wc[4 * q + 3] + t1 * Wc[16 + 4 * q + 3] + bc[4 * q + 3];
            o[q] = v;
        }
    }
}

// ---------------- fallback path (round-1 proven, push atomics) ----------------

__global__ void k_count(const int* __restrict__ dst, int* __restrict__ cnt, int e) {
    int i = blockIdx.x * blockDim.x + threadIdx.x;
    if (i < e) atomicAdd(&cnt[dst[i]], 1);
}

__global__ void k_dinv_i(const int* __restrict__ cnt, float* __restrict__ dinv, int n) {
    int i = blockIdx.x * blockDim.x + threadIdx.x;
    if (i < n) dinv[i] = rsqrtf(1.0f + (float)cnt[i]);
}

__global__ void f_linear1(const float* __restrict__ x, const float* __restrict__ W1,
                          const float* __restrict__ dinv,
                          float* __restrict__ h, float* __restrict__ agg, int n) {
    int lane = threadIdx.x & 63;
    int wave = blockIdx.x * (blockDim.x >> 6) + (threadIdx.x >> 6);
    int nwaves = gridDim.x * (blockDim.x >> 6);
    float4 w0 = ((const float4*)W1)[2 * lane];
    float4 w1 = ((const float4*)W1)[2 * lane + 1];
    for (int row = wave; row < n; row += nwaves) {
        float2 xv = ((const float2*)(x + (size_t)row * 128))[lane];
        float p0 = xv.x * w0.x + xv.y * w1.x;
        float p1 = xv.x * w0.y + xv.y * w1.y;
        float p2 = xv.x * w0.z + xv.y * w1.z;
        float p3 = xv.x * w0.w + xv.y * w1.w;
#pragma unroll
        for (int off = 32; off; off >>= 1) {
            p0 += __shfl_xor(p0, off, 64);
            p1 += __shfl_xor(p1, off, 64);
            p2 += __shfl_xor(p2, off, 64);
            p3 += __shfl_xor(p3, off, 64);
        }
        if (lane == 0) {
            float dv = dinv[row]; float dv2 = dv * dv;
            ((float4*)h)[row] = make_float4(p0, p1, p2, p3);
            ((float4*)agg)[row] = make_float4(dv2 * p0, dv2 * p1, dv2 * p2, dv2 * p3);
        }
    }
}

__global__ void k_edge4(const int* __restrict__ src, const int* __restrict__ dst,
                        const float* __restrict__ dinv, const float* __restrict__ h,
                        float* __restrict__ agg, int e) {
    int i = blockIdx.x * blockDim.x + threadIdx.x;
    if (i >= e) return;
    int s = src[i], d = dst[i];
    float w = dinv[s] * dinv[d];
    float4 hv = ((const float4*)h)[s];
    float* a = agg + 4 * (size_t)d;
    unsafeAtomicAdd(a + 0, w * hv.x);
    unsafeAtomicAdd(a + 1, w * hv.y);
    unsafeAtomicAdd(a + 2, w * hv.z);
    unsafeAtomicAdd(a + 3, w * hv.w);
}

__global__ void k_edge2(const int* __restrict__ src, const int* __restrict__ dst,
                        const float* __restrict__ dinv, const float* __restrict__ h,
                        float* __restrict__ agg, int e) {
    int i = blockIdx.x * blockDim.x + threadIdx.x;
    if (i >= e) return;
    int s = src[i], d = dst[i];
    float w = dinv[s] * dinv[d];
    float2 hv = ((const float2*)h)[s];
    float* a = agg + 2 * (size_t)d;
    unsafeAtomicAdd(a + 0, w * hv.x);
    unsafeAtomicAdd(a + 1, w * hv.y);
}

__global__ void k_fin44(float* __restrict__ h, float* __restrict__ agg,
                        const float* __restrict__ dinv,
                        const float* __restrict__ W, const float* __restrict__ b, int n) {
    int i = blockIdx.x * blockDim.x + threadIdx.x;
    if (i >= n) return;
    float4 a = ((const float4*)agg)[i];
    float t0 = tanhf(a.x + b[0]);
    float t1 = tanhf(a.y + b[1]);
    float t2 = tanhf(a.z + b[2]);
    float t3 = tanhf(a.w + b[3]);
    float hn[4];
#pragma unroll
    for (int k = 0; k < 4; k++)
        hn[k] = t0 * W[k] + t1 * W[4 + k] + t2 * W[8 + k] + t3 * W[12 + k];
    float dv = dinv[i], dv2 = dv * dv;
    ((float4*)h)[i] = make_float4(hn[0], hn[1], hn[2], hn[3]);
    ((float4*)agg)[i] = make_float4(dv2 * hn[0], dv2 * hn[1], dv2 * hn[2], dv2 * hn[3]);
}

__global__ void k_fin42(const float* __restrict__ agg, float* __restrict__ h3,
                        float* __restrict__ agg3, const float* __restrict__ dinv,
                        const float* __restrict__ W, const float* __restrict__ b, int n) {
    int i = blockIdx.x * blockDim.x + threadIdx.x;
    if (i >= n) return;
    float4 a = ((const float4*)agg)[i];
    float t0 = tanhf(a.x + b[0]);
    float t1 = tanhf(a.y + b[1]);
    float t2 = tanhf(a.z + b[2]);
    float t3 = tanhf(a.w + b[3]);
    float h0 = t0 * W[0] + t1 * W[2] + t2 * W[4] + t3 * W[6];
    float h1 = t0 * W[1] + t1 * W[3] + t2 * W[5] + t3 * W[7];
    float dv = dinv[i], dv2 = dv * dv;
    ((float2*)h3)[i] = make_float2(h0, h1);
    ((float2*)agg3)[i] = make_float2(dv2 * h0, dv2 * h1);
}

__global__ void k_final_old(const float* __restrict__ agg3,
                            const float* __restrict__ Wc, const float* __restrict__ b3,
                            const float* __restrict__ bc,
                            float* __restrict__ out, float* __restrict__ hout, int n) {
    int i = blockIdx.x * blockDim.x + threadIdx.x;
    if (i >= n) return;
    float2 a = ((const float2*)agg3)[i];
    float t0 = tanhf(a.x + b3[0]);
    float t1 = tanhf(a.y + b3[1]);
    ((float2*)hout)[i] = make_float2(t0, t1);
    float4* o = (float4*)(out + (size_t)i * 16);
#pragma unroll
    for (int q = 0; q < 4; q++) {
        float4 v;
        v.x = t0 * Wc[4 * q + 0] + t1 * Wc[16 + 4 * q + 0] + bc[4 * q + 0];
        v.y = t0 * Wc[4 * q + 1] + t1 * Wc[16 + 4 * q + 1] + bc[4 * q + 1];
        v.z = t0 * Wc[4 * q + 2] + t1 * Wc[16 + 4 * q + 2] + bc[4 * q + 2];
        v.w = t0 * Wc[4 * q + 3] + t1 * Wc[16 + 4 * q + 3] + bc[4 * q + 3];
        o[q] = v;
    }
}

// ---------------- launcher ----------------

extern "C" void kernel_launch(void* const* d_in, const int* in_sizes, int n_in,
                              void* d_out, int out_size, void* d_ws, size_t ws_size,
                              hipStream_t stream) {
    const float* x   = (const float*)d_in[0];
    const float* W1  = (const float*)d_in[1];
    const float* b1  = (const float*)d_in[2];
    const float* W2  = (const float*)d_in[3];
    const float* b2  = (const float*)d_in[4];
    const float* W3  = (const float*)d_in[5];
    const float* b3  = (const float*)d_in[6];
    const float* Wc  = (const float*)d_in[7];
    const float* bc  = (const float*)d_in[8];
    const int* eidx  = (const int*)d_in[9];

    const int n = in_sizes[0] / 128;   // 200000
    const int e = in_sizes[9] / 2;     // 6400000
    const int* src = eidx;
    const int* dst = eidx + e;

    float* out_c = (float*)d_out;                   // [n,16]
    float* out_h = (float*)d_out + 16 * (size_t)n;  // [n,2]

    const int B = 256;
    const int gn = (n + B - 1) / B;
    const int ge = (e + B - 1) / B;
    const int nbE = (e + EPB - 1) / EPB;            // build blocks

    size_t nP = ((size_t)n + 3) & ~(size_t)3;

    // fast-path workspace layout
    int* csrp    = (int*)d_ws;                // NR*CAP
    int* cursor  = csrp + (size_t)NR * CAP;   // NR*16 (padded bins)
    float* dinv  = (float*)(cursor + NR * 16);
    float* g1    = dinv + nP;                 // 4nP
    float* g2    = g1 + 4 * nP;               // 4nP
    float* g3    = g2 + 4 * nP;               // 2nP
    size_t need  = (size_t)((char*)(g3 + 2 * nP) - (char*)d_ws);

    bool fast = (ws_size >= need) && (n <= NR * RNG) && (n < (1 << 18));

    if (fast) {
        k_initcur<<<(NR + 255) / 256, 256, 0, stream>>>(cursor);
        k_build<<<nbE, HB, 0, stream>>>(src, dst, cursor, csrp, e);
        k_bdeg<<<NR, AB, 0, stream>>>(csrp, cursor, dinv, n);

        k_linear1<<<(n + 3) / 4, B, 0, stream>>>(x, W1, dinv, (float4*)g1, n);
        k_bagg44<<<NR, AB, 0, stream>>>(csrp, cursor, dinv, (const float4*)g1,
                                        (float4*)g2, W2, b1, n);
        k_bagg42<<<NR, AB, 0, stream>>>(csrp, cursor, dinv, (const float4*)g2,
                                        (float2*)g3, W3, b2, n);
        k_bagg2out<<<NR, AB, 0, stream>>>(csrp, cursor, dinv, (const float2*)g3,
                                          b3, Wc, bc, out_c, (float2*)out_h, n);
    } else {
        // fallback: push-atomic path (~11MB ws)
        int* fcnt   = (int*)d_ws;
        float* fdnv = (float*)d_ws + nP;
        float* h    = fdnv + nP;
        float* agg  = h + 4 * nP;
        float* h3   = agg + 4 * nP;
        float* agg3 = h3 + 2 * nP;

        hipMemsetAsync(fcnt, 0, (size_t)n * sizeof(int), stream);
        k_count<<<ge, B, 0, stream>>>(dst, fcnt, e);
        k_dinv_i<<<gn, B, 0, stream>>>(fcnt, fdnv, n);
        f_linear1<<<(n + 3) / 4, B, 0, stream>>>(x, W1, fdnv, h, agg, n);
        k_edge4<<<ge, B, 0, stream>>>(src, dst, fdnv, h, agg, e);
        k_fin44<<<gn, B, 0, stream>>>(h, agg, fdnv, W2, b1, n);
        k_edge4<<<ge, B, 0, stream>>>(src, dst, fdnv, h, agg, e);
        k_fin42<<<gn, B, 0, stream>>>(agg, h3, agg3, fdnv, W3, b2, n);
        k_edge2<<<ge, B, 0, stream>>>(src, dst, fdnv, h3, agg3, e);
        k_final_old<<<gn, B, 0, stream>>>(agg3, Wc, b3, bc, out_c, out_h, n);
    }
}

// Round 9
// 441.772 us; speedup vs baseline: 1.6659x; 1.4024x over previous
//
#include <hip/hip_runtime.h>
#include <math.h>

// GCN 3-layer + classifier — round 9: dst-SORTED bins + register run-reduction.
//
// Empirical law (rounds 1-8): each address-divergent vmem instruction
// (divergent global load/store, LDS atomic) costs ~160cy of a serialized
// per-CU front-end; coalesced vmem + plain ds_read/write are cheap. All edge
// kernels fit: cost = 160 x (divergent instructions per edge).
// Fix: (a) pass2 sorts each 400-node bin's edges by local dst (counting sort
// in LDS; also emits dinv — bdeg pass deleted); (b) bagg kernels give each
// lane a contiguous region of sorted edges, accumulate same-dst runs in
// registers, queue per-run partials in LDS (cheap ds_write), flush with
// wave-batched LDS atomics only when __any(qc>=Q-3). Expensive instr/edge:
// 0.078 -> ~0.023. Correctness does not depend on sortedness (queue merges
// any order via atomics).

#define NR 500
#define RNG 400
#define CAP 16384            // slots per bin (expect ~12800 +- 113)
#define HB 1024              // build threads
#define EPT 8                // build edges per thread
#define EPB (HB * EPT)       // 8192 edges per build block
#define SCAP 14336           // sortbin LDS buffer (mean+13 sigma)
#define Q 8                  // per-lane queue slots

// ---------------- build (pass1: bin by dst/400) ----------------

__global__ void k_initcur(int* __restrict__ cursor) {
    int t = blockIdx.x * blockDim.x + threadIdx.x;
    if (t < NR) cursor[t * 16] = t * CAP;
}

__global__ __launch_bounds__(HB) void k_build(const int* __restrict__ src,
                                              const int* __restrict__ dst,
                                              int* __restrict__ cursor,
                                              int* __restrict__ csrp, int e) {
    __shared__ int hist[NR];
    __shared__ int scn[HB];
    __shared__ int start[NR + 1];
    __shared__ int gbase[NR];
    __shared__ int cur[NR];
    __shared__ int buf[EPB];

    int t = threadIdx.x;
    for (int i = t; i < NR; i += HB) hist[i] = 0;
    __syncthreads();

    int ds[EPT], sr[EPT];
    int base = blockIdx.x * EPB;
#pragma unroll
    for (int k = 0; k < 2; k++) {
        int idx = base + k * HB * 4 + t * 4;
        if (idx + 3 < e) {
            int4 d4 = *(const int4*)(dst + idx);
            int4 s4 = *(const int4*)(src + idx);
            ds[4 * k + 0] = d4.x; ds[4 * k + 1] = d4.y; ds[4 * k + 2] = d4.z; ds[4 * k + 3] = d4.w;
            sr[4 * k + 0] = s4.x; sr[4 * k + 1] = s4.y; sr[4 * k + 2] = s4.z; sr[4 * k + 3] = s4.w;
        } else {
#pragma unroll
            for (int j = 0; j < 4; j++) {
                int i2 = idx + j;
                if (i2 < e) { ds[4 * k + j] = dst[i2]; sr[4 * k + j] = src[i2]; }
                else ds[4 * k + j] = -1;
            }
        }
    }
#pragma unroll
    for (int k = 0; k < EPT; k++)
        if (ds[k] >= 0) atomicAdd(&hist[ds[k] / RNG], 1);
    __syncthreads();

    scn[t] = (t < NR) ? hist[t] : 0;
    __syncthreads();
    for (int off = 1; off < HB; off <<= 1) {
        int add = (t >= off) ? scn[t - off] : 0;
        __syncthreads();
        scn[t] += add;
        __syncthreads();
    }
    if (t < NR) {
        int c = hist[t];
        int st = scn[t] - c;
        start[t] = st;
        cur[t] = st;
        gbase[t] = c ? atomicAdd(&cursor[t * 16], c) : 0;
    }
    if (t == 0) start[NR] = scn[NR - 1];
    __syncthreads();

#pragma unroll
    for (int k = 0; k < EPT; k++) {
        if (ds[k] >= 0) {
            int bin = ds[k] / RNG;
            int p = atomicAdd(&cur[bin], 1);
            buf[p] = (sr[k] << 9) | (ds[k] - bin * RNG);
        }
    }
    __syncthreads();

    int total = start[NR];
    for (int j = t; j < total; j += HB) {
        int lo = 0, hi = NR;
        while (hi - lo > 1) {
            int mid = (lo + hi) >> 1;
            if (start[mid] <= j) lo = mid; else hi = mid;
        }
        int g = gbase[lo] + (j - start[lo]);
        if (g < (lo + 1) * CAP) csrp[g] = buf[j];
    }
}

// ---------------- pass2: per-bin counting sort by local dst + dinv ----------------

__global__ __launch_bounds__(1024) void k_sortbin(int* __restrict__ csrp,
                                                  const int* __restrict__ cursor,
                                                  float* __restrict__ dinv, int n) {
    __shared__ int deg[RNG];
    __shared__ int off[RNG];
    __shared__ int cur[RNG];
    __shared__ int sbuf[SCAP];
    int t = threadIdx.x, b = blockIdx.x;
    int s0 = b * CAP;
    int cnt = cursor[b * 16] - s0;
    if (cnt < 0) cnt = 0; if (cnt > CAP) cnt = CAP;

    for (int i = t; i < RNG; i += 1024) deg[i] = 0;
    __syncthreads();
    for (int j = t; j < cnt; j += 1024)
        atomicAdd(&deg[csrp[s0 + j] & 511], 1);
    __syncthreads();

    // inclusive scan over RNG entries
    if (t < RNG) off[t] = deg[t];
    __syncthreads();
    for (int d = 1; d < RNG; d <<= 1) {
        int u = 0;
        if (t < RNG && t >= d) u = off[t - d];
        __syncthreads();
        if (t < RNG) off[t] += u;
        __syncthreads();
    }
    if (t < RNG) cur[t] = off[t] - deg[t];   // exclusive
    __syncthreads();

    // rank + scatter into LDS (order within a node irrelevant — sums commute)
    for (int j = t; j < cnt; j += 1024) {
        int p = csrp[s0 + j];
        int r = atomicAdd(&cur[p & 511], 1);
        if (r < SCAP) sbuf[r] = p;
    }
    __syncthreads();
    int lim = (cnt < SCAP) ? cnt : SCAP;
    for (int j = t; j < lim; j += 1024)
        csrp[s0 + j] = sbuf[j];

    int basen = b * RNG;
    for (int i = t; i < RNG; i += 1024) {
        int node = basen + i;
        if (node < n) dinv[node] = rsqrtf(1.0f + (float)deg[i]);
    }
}

// ---------------- layer 1 linear: g1 = dinv * (x @ W1), wave-per-row ----------------

__global__ void k_linear1(const float* __restrict__ x, const float* __restrict__ W1,
                          const float* __restrict__ dinv, float4* __restrict__ g1, int n) {
    int lane = threadIdx.x & 63;
    int wave = blockIdx.x * (blockDim.x >> 6) + (threadIdx.x >> 6);
    int nwaves = gridDim.x * (blockDim.x >> 6);

    float4 w0 = ((const float4*)W1)[2 * lane];
    float4 w1 = ((const float4*)W1)[2 * lane + 1];

    for (int row = wave; row < n; row += nwaves) {
        float2 xv = ((const float2*)(x + (size_t)row * 128))[lane];
        float p0 = xv.x * w0.x + xv.y * w1.x;
        float p1 = xv.x * w0.y + xv.y * w1.y;
        float p2 = xv.x * w0.z + xv.y * w1.z;
        float p3 = xv.x * w0.w + xv.y * w1.w;
#pragma unroll
        for (int off = 32; off; off >>= 1) {
            p0 += __shfl_xor(p0, off, 64);
            p1 += __shfl_xor(p1, off, 64);
            p2 += __shfl_xor(p2, off, 64);
            p3 += __shfl_xor(p3, off, 64);
        }
        if (lane == 0) {
            float dv = dinv[row];
            g1[row] = make_float4(dv * p0, dv * p1, dv * p2, dv * p3);
        }
    }
}

// ---------------- sorted-run bucketed aggregation ----------------

#define PUSH4() { qd[qc * 256 + t] = cd; \
    qv[(qc * 4 + 0) * 256 + t] = a0; qv[(qc * 4 + 1) * 256 + t] = a1; \
    qv[(qc * 4 + 2) * 256 + t] = a2; qv[(qc * 4 + 3) * 256 + t] = a3; qc++; }
#define EDGE4(di, gv) { int d_ = (di) & 511; \
    if (d_ != cd) { if (cd >= 0) PUSH4(); cd = d_; a0 = gv.x; a1 = gv.y; a2 = gv.z; a3 = gv.w; } \
    else { a0 += gv.x; a1 += gv.y; a2 += gv.z; a3 += gv.w; } }
#define FLUSH4() { for (int q = 0; q < Q; q++) { if (q < qc) { int dd = qd[q * 256 + t]; \
    atomicAdd(&acc[dd * 5 + 0], qv[(q * 4 + 0) * 256 + t]); \
    atomicAdd(&acc[dd * 5 + 1], qv[(q * 4 + 1) * 256 + t]); \
    atomicAdd(&acc[dd * 5 + 2], qv[(q * 4 + 2) * 256 + t]); \
    atomicAdd(&acc[dd * 5 + 3], qv[(q * 4 + 3) * 256 + t]); } } qc = 0; }

// common edge loop: fills acc[RNG*5] with neighbor sums of 4-wide gin
#define EDGELOOP4() \
    int s0 = b * CAP; \
    int cnt = cursor[b * 16] - s0; if (cnt < 0) cnt = 0; if (cnt > CAP) cnt = CAP; \
    int per = (((cnt + 255) >> 8) + 3) & ~3; \
    int lo = s0 + t * per; \
    int hi = lo + per; int eE = s0 + cnt; if (hi > eE) hi = eE; \
    int cd = -1; float a0 = 0, a1 = 0, a2 = 0, a3 = 0; \
    int qc = 0; \
    for (int j = lo; j < hi; j += 4) { \
        int4 p = *(const int4*)(csrp + j); \
        int m = hi - j; \
        int i1 = (m > 1) ? p.y : p.x; \
        int i2 = (m > 2) ? p.z : p.x; \
        int i3 = (m > 3) ? p.w : p.x; \
        float4 g0 = gin[(unsigned)p.x >> 9]; \
        float4 g1 = gin[(unsigned)i1 >> 9]; \
        float4 g2 = gin[(unsigned)i2 >> 9]; \
        float4 g3 = gin[(unsigned)i3 >> 9]; \
        EDGE4(p.x, g0); \
        if (m > 1) EDGE4(i1, g1); \
        if (m > 2) EDGE4(i2, g2); \
        if (m > 3) EDGE4(i3, g3); \
        if (__any(qc >= Q - 3)) FLUSH4(); \
    } \
    if (cd >= 0) PUSH4(); \
    FLUSH4(); \
    __syncthreads();

__global__ __launch_bounds__(256) void k_bagg44s(const int* __restrict__ csrp,
                                                 const int* __restrict__ cursor,
                                                 const float* __restrict__ dinv,
                                                 const float4* __restrict__ gin,
                                                 float4* __restrict__ gout,
                                                 const float* __restrict__ W,
                                                 const float* __restrict__ bv, int n) {
    __shared__ float acc[RNG * 5];        // 8KB
    __shared__ float qv[Q * 4 * 256];     // 32KB
    __shared__ int   qd[Q * 256];         // 8KB
    int t = threadIdx.x, b = blockIdx.x;
    for (int i = t; i < RNG * 5; i += 256) acc[i] = 0.0f;
    __syncthreads();
    EDGELOOP4();
    int basen = b * RNG;
    for (int i = t; i < RNG; i += 256) {
        int node = basen + i;
        if (node >= n) continue;
        float4 gs = gin[node];
        float dv = dinv[node];
        float t0 = tanhf(dv * (gs.x + acc[i * 5 + 0]) + bv[0]);
        float t1 = tanhf(dv * (gs.y + acc[i * 5 + 1]) + bv[1]);
        float t2 = tanhf(dv * (gs.z + acc[i * 5 + 2]) + bv[2]);
        float t3 = tanhf(dv * (gs.w + acc[i * 5 + 3]) + bv[3]);
        float4 o;
        o.x = dv * (t0 * W[0] + t1 * W[4] + t2 * W[8]  + t3 * W[12]);
        o.y = dv * (t0 * W[1] + t1 * W[5] + t2 * W[9]  + t3 * W[13]);
        o.z = dv * (t0 * W[2] + t1 * W[6] + t2 * W[10] + t3 * W[14]);
        o.w = dv * (t0 * W[3] + t1 * W[7] + t2 * W[11] + t3 * W[15]);
        gout[node] = o;
    }
}

__global__ __launch_bounds__(256) void k_bagg42s(const int* __restrict__ csrp,
                                                 const int* __restrict__ cursor,
                                                 const float* __restrict__ dinv,
                                                 const float4* __restrict__ gin,
                                                 float2* __restrict__ gout,
                                                 const float* __restrict__ W,
                                                 const float* __restrict__ bv, int n) {
    __shared__ float acc[RNG * 5];
    __shared__ float qv[Q * 4 * 256];
    __shared__ int   qd[Q * 256];
    int t = threadIdx.x, b = blockIdx.x;
    for (int i = t; i < RNG * 5; i += 256) acc[i] = 0.0f;
    __syncthreads();
    EDGELOOP4();
    int basen = b * RNG;
    for (int i = t; i < RNG; i += 256) {
        int node = basen + i;
        if (node >= n) continue;
        float4 gs = gin[node];
        float dv = dinv[node];
        float t0 = tanhf(dv * (gs.x + acc[i * 5 + 0]) + bv[0]);
        float t1 = tanhf(dv * (gs.y + acc[i * 5 + 1]) + bv[1]);
        float t2 = tanhf(dv * (gs.z + acc[i * 5 + 2]) + bv[2]);
        float t3 = tanhf(dv * (gs.w + acc[i * 5 + 3]) + bv[3]);
        float h0 = t0 * W[0] + t1 * W[2] + t2 * W[4] + t3 * W[6];
        float h1 = t0 * W[1] + t1 * W[3] + t2 * W[5] + t3 * W[7];
        gout[node] = make_float2(dv * h0, dv * h1);
    }
}

#define PUSH2() { qd[qc * 256 + t] = cd; \
    qv[(qc * 2 + 0) * 256 + t] = a0; qv[(qc * 2 + 1) * 256 + t] = a1; qc++; }
#define EDGE2(di, gv) { int d_ = (di) & 511; \
    if (d_ != cd) { if (cd >= 0) PUSH2(); cd = d_; a0 = gv.x; a1 = gv.y; } \
    else { a0 += gv.x; a1 += gv.y; } }
#define FLUSH2() { for (int q = 0; q < Q; q++) { if (q < qc) { int dd = qd[q * 256 + t]; \
    atomicAdd(&acc[dd * 3 + 0], qv[(q * 2 + 0) * 256 + t]); \
    atomicAdd(&acc[dd * 3 + 1], qv[(q * 2 + 1) * 256 + t]); } } qc = 0; }

__global__ __launch_bounds__(256) void k_bagg2outs(const int* __restrict__ csrp,
                                                   const int* __restrict__ cursor,
                                                   const float* __restrict__ dinv,
                                                   const float2* __restrict__ gin,
                                                   const float* __restrict__ b3,
                                                   const float* __restrict__ Wc,
                                                   const float* __restrict__ bc,
                                                   float* __restrict__ out,
                                                   float2* __restrict__ hout, int n) {
    __shared__ float acc[RNG * 3];        // 4.8KB
    __shared__ float qv[Q * 2 * 256];     // 16KB
    __shared__ int   qd[Q * 256];         // 8KB
    int t = threadIdx.x, b = blockIdx.x;
    for (int i = t; i < RNG * 3; i += 256) acc[i] = 0.0f;
    __syncthreads();
    int s0 = b * CAP;
    int cnt = cursor[b * 16] - s0; if (cnt < 0) cnt = 0; if (cnt > CAP) cnt = CAP;
    int per = (((cnt + 255) >> 8) + 3) & ~3;
    int lo = s0 + t * per;
    int hi = lo + per; int eE = s0 + cnt; if (hi > eE) hi = eE;
    int cd = -1; float a0 = 0, a1 = 0;
    int qc = 0;
    for (int j = lo; j < hi; j += 4) {
        int4 p = *(const int4*)(csrp + j);
        int m = hi - j;
        int i1 = (m > 1) ? p.y : p.x;
        int i2 = (m > 2) ? p.z : p.x;
        int i3 = (m > 3) ? p.w : p.x;
        float2 g0 = gin[(unsigned)p.x >> 9];
        float2 g1 = gin[(unsigned)i1 >> 9];
        float2 g2 = gin[(unsigned)i2 >> 9];
        float2 g3 = gin[(unsigned)i3 >> 9];
        EDGE2(p.x, g0);
        if (m > 1) EDGE2(i1, g1);
        if (m > 2) EDGE2(i2, g2);
        if (m > 3) EDGE2(i3, g3);
        if (__any(qc >= Q - 3)) FLUSH2();
    }
    if (cd >= 0) PUSH2();
    FLUSH2();
    __syncthreads();
    int basen = b * RNG;
    for (int i = t; i < RNG; i += 256) {
        int node = basen + i;
        if (node >= n) continue;
        float2 gs = gin[node];
        float dv = dinv[node];
        float t0 = tanhf(dv * (gs.x + acc[i * 3 + 0]) + b3[0]);
        float t1 = tanhf(dv * (gs.y + acc[i * 3 + 1]) + b3[1]);
        hout[node] = make_float2(t0, t1);
        float4* o = (float4*)(out + (size_t)node * 16);
#pragma unroll
        for (int q = 0; q < 4; q++) {
            float4 v;
            v.x = t0 * Wc[4 * q + 0] + t1 * Wc[16 + 4 * q + 0] + bc[4 * q + 0];
            v.y = t0 * Wc[4 * q + 1] + t1 * Wc[16 + 4 * q + 1] + bc[4 * q + 1];
            v.z = t0 * Wc[4 * q + 2] + t1 * Wc[16 + 4 * q + 2] + bc[4 * q + 2];
            v.w = t0 * Wc[4 * q + 3] + t1 * Wc[16 + 4 * q + 3] + bc[4 * q + 3];
            o[q] = v;
        }
    }
}

// ---------------- fallback path (round-1 proven, push atomics) ----------------

__global__ void k_count(const int* __restrict__ dst, int* __restrict__ cnt, int e) {
    int i = blockIdx.x * blockDim.x + threadIdx.x;
    if (i < e) atomicAdd(&cnt[dst[i]], 1);
}

__global__ void k_dinv_i(const int* __restrict__ cnt, float* __restrict__ dinv, int n) {
    int i = blockIdx.x * blockDim.x + threadIdx.x;
    if (i < n) dinv[i] = rsqrtf(1.0f + (float)cnt[i]);
}

__global__ void f_linear1(const float* __restrict__ x, const float* __restrict__ W1,
                          const float* __restrict__ dinv,
                          float* __restrict__ h, float* __restrict__ agg, int n) {
    int lane = threadIdx.x & 63;
    int wave = blockIdx.x * (blockDim.x >> 6) + (threadIdx.x >> 6);
    int nwaves = gridDim.x * (blockDim.x >> 6);
    float4 w0 = ((const float4*)W1)[2 * lane];
    float4 w1 = ((const float4*)W1)[2 * lane + 1];
    for (int row = wave; row < n; row += nwaves) {
        float2 xv = ((const float2*)(x + (size_t)row * 128))[lane];
        float p0 = xv.x * w0.x + xv.y * w1.x;
        float p1 = xv.x * w0.y + xv.y * w1.y;
        float p2 = xv.x * w0.z + xv.y * w1.z;
        float p3 = xv.x * w0.w + xv.y * w1.w;
#pragma unroll
        for (int off = 32; off; off >>= 1) {
            p0 += __shfl_xor(p0, off, 64);
            p1 += __shfl_xor(p1, off, 64);
            p2 += __shfl_xor(p2, off, 64);
            p3 += __shfl_xor(p3, off, 64);
        }
        if (lane == 0) {
            float dv = dinv[row]; float dv2 = dv * dv;
            ((float4*)h)[row] = make_float4(p0, p1, p2, p3);
            ((float4*)agg)[row] = make_float4(dv2 * p0, dv2 * p1, dv2 * p2, dv2 * p3);
        }
    }
}

__global__ void k_edge4(const int* __restrict__ src, const int* __restrict__ dst,
                        const float* __restrict__ dinv, const float* __restrict__ h,
                        float* __restrict__ agg, int e) {
    int i = blockIdx.x * blockDim.x + threadIdx.x;
    if (i >= e) return;
    int s = src[i], d = dst[i];
    float w = dinv[s] * dinv[d];
    float4 hv = ((const float4*)h)[s];
    float* a = agg + 4 * (size_t)d;
    unsafeAtomicAdd(a + 0, w * hv.x);
    unsafeAtomicAdd(a + 1, w * hv.y);
    unsafeAtomicAdd(a + 2, w * hv.z);
    unsafeAtomicAdd(a + 3, w * hv.w);
}

__global__ void k_edge2(const int* __restrict__ src, const int* __restrict__ dst,
                        const float* __restrict__ dinv, const float* __restrict__ h,
                        float* __restrict__ agg, int e) {
    int i = blockIdx.x * blockDim.x + threadIdx.x;
    if (i >= e) return;
    int s = src[i], d = dst[i];
    float w = dinv[s] * dinv[d];
    float2 hv = ((const float2*)h)[s];
    float* a = agg + 2 * (size_t)d;
    unsafeAtomicAdd(a + 0, w * hv.x);
    unsafeAtomicAdd(a + 1, w * hv.y);
}

__global__ void k_fin44(float* __restrict__ h, float* __restrict__ agg,
                        const float* __restrict__ dinv,
                        const float* __restrict__ W, const float* __restrict__ b, int n) {
    int i = blockIdx.x * blockDim.x + threadIdx.x;
    if (i >= n) return;
    float4 a = ((const float4*)agg)[i];
    float t0 = tanhf(a.x + b[0]);
    float t1 = tanhf(a.y + b[1]);
    float t2 = tanhf(a.z + b[2]);
    float t3 = tanhf(a.w + b[3]);
    float hn[4];
#pragma unroll
    for (int k = 0; k < 4; k++)
        hn[k] = t0 * W[k] + t1 * W[4 + k] + t2 * W[8 + k] + t3 * W[12 + k];
    float dv = dinv[i], dv2 = dv * dv;
    ((float4*)h)[i] = make_float4(hn[0], hn[1], hn[2], hn[3]);
    ((float4*)agg)[i] = make_float4(dv2 * hn[0], dv2 * hn[1], dv2 * hn[2], dv2 * hn[3]);
}

__global__ void k_fin42(const float* __restrict__ agg, float* __restrict__ h3,
                        float* __restrict__ agg3, const float* __restrict__ dinv,
                        const float* __restrict__ W, const float* __restrict__ b, int n) {
    int i = blockIdx.x * blockDim.x + threadIdx.x;
    if (i >= n) return;
    float4 a = ((const float4*)agg)[i];
    float t0 = tanhf(a.x + b[0]);
    float t1 = tanhf(a.y + b[1]);
    float t2 = tanhf(a.z + b[2]);
    float t3 = tanhf(a.w + b[3]);
    float h0 = t0 * W[0] + t1 * W[2] + t2 * W[4] + t3 * W[6];
    float h1 = t0 * W[1] + t1 * W[3] + t2 * W[5] + t3 * W[7];
    float dv = dinv[i], dv2 = dv * dv;
    ((float2*)h3)[i] = make_float2(h0, h1);
    ((float2*)agg3)[i] = make_float2(dv2 * h0, dv2 * h1);
}

__global__ void k_final_old(const float* __restrict__ agg3,
                            const float* __restrict__ Wc, const float* __restrict__ b3,
                            const float* __restrict__ bc,
                            float* __restrict__ out, float* __restrict__ hout, int n) {
    int i = blockIdx.x * blockDim.x + threadIdx.x;
    if (i >= n) return;
    float2 a = ((const float2*)agg3)[i];
    float t0 = tanhf(a.x + b3[0]);
    float t1 = tanhf(a.y + b3[1]);
    ((float2*)hout)[i] = make_float2(t0, t1);
    float4* o = (float4*)(out + (size_t)i * 16);
#pragma unroll
    for (int q = 0; q < 4; q++) {
        float4 v;
        v.x = t0 * Wc[4 * q + 0] + t1 * Wc[16 + 4 * q + 0] + bc[4 * q + 0];
        v.y = t0 * Wc[4 * q + 1] + t1 * Wc[16 + 4 * q + 1] + bc[4 * q + 1];
        v.z = t0 * Wc[4 * q + 2] + t1 * Wc[16 + 4 * q + 2] + bc[4 * q + 2];
        v.w = t0 * Wc[4 * q + 3] + t1 * Wc[16 + 4 * q + 3] + bc[4 * q + 3];
        o[q] = v;
    }
}

// ---------------- launcher ----------------

extern "C" void kernel_launch(void* const* d_in, const int* in_sizes, int n_in,
                              void* d_out, int out_size, void* d_ws, size_t ws_size,
                              hipStream_t stream) {
    const float* x   = (const float*)d_in[0];
    const float* W1  = (const float*)d_in[1];
    const float* b1  = (const float*)d_in[2];
    const float* W2  = (const float*)d_in[3];
    const float* b2  = (const float*)d_in[4];
    const float* W3  = (const float*)d_in[5];
    const float* b3  = (const float*)d_in[6];
    const float* Wc  = (const float*)d_in[7];
    const float* bc  = (const float*)d_in[8];
    const int* eidx  = (const int*)d_in[9];

    const int n = in_sizes[0] / 128;   // 200000
    const int e = in_sizes[9] / 2;     // 6400000
    const int* src = eidx;
    const int* dst = eidx + e;

    float* out_c = (float*)d_out;                   // [n,16]
    float* out_h = (float*)d_out + 16 * (size_t)n;  // [n,2]

    const int B = 256;
    const int gn = (n + B - 1) / B;
    const int ge = (e + B - 1) / B;
    const int nbE = (e + EPB - 1) / EPB;            // build blocks

    size_t nP = ((size_t)n + 3) & ~(size_t)3;

    // fast-path workspace layout (csrp has 4096-int slack for tail overreads)
    int* csrp    = (int*)d_ws;                         // NR*CAP + 4096
    int* cursor  = csrp + (size_t)NR * CAP + 4096;     // NR*16
    float* dinv  = (float*)(cursor + NR * 16);
    float* g1    = dinv + nP;                 // 4nP
    float* g2    = g1 + 4 * nP;               // 4nP
    float* g3    = g2 + 4 * nP;               // 2nP
    size_t need  = (size_t)((char*)(g3 + 2 * nP) - (char*)d_ws);

    bool fast = (ws_size >= need) && (n <= NR * RNG) && (n < (1 << 18));

    if (fast) {
        k_initcur<<<(NR + 255) / 256, 256, 0, stream>>>(cursor);
        k_build<<<nbE, HB, 0, stream>>>(src, dst, cursor, csrp, e);
        k_sortbin<<<NR, 1024, 0, stream>>>(csrp, cursor, dinv, n);

        k_linear1<<<(n + 3) / 4, B, 0, stream>>>(x, W1, dinv, (float4*)g1, n);
        k_bagg44s<<<NR, 256, 0, stream>>>(csrp, cursor, dinv, (const float4*)g1,
                                          (float4*)g2, W2, b1, n);
        k_bagg42s<<<NR, 256, 0, stream>>>(csrp, cursor, dinv, (const float4*)g2,
                                          (float2*)g3, W3, b2, n);
        k_bagg2outs<<<NR, 256, 0, stream>>>(csrp, cursor, dinv, (const float2*)g3,
                                            b3, Wc, bc, out_c, (float2*)out_h, n);
    } else {
        // fallback: push-atomic path (~11MB ws)
        int* fcnt   = (int*)d_ws;
        float* fdnv = (float*)d_ws + nP;
        float* h    = fdnv + nP;
        float* agg  = h + 4 * nP;
        float* h3   = agg + 4 * nP;
        float* agg3 = h3 + 2 * nP;

        hipMemsetAsync(fcnt, 0, (size_t)n * sizeof(int), stream);
        k_count<<<ge, B, 0, stream>>>(dst, fcnt, e);
        k_dinv_i<<<gn, B, 0, stream>>>(fcnt, fdnv, n);
        f_linear1<<<(n + 3) / 4, B, 0, stream>>>(x, W1, fdnv, h, agg, n);
        k_edge4<<<ge, B, 0, stream>>>(src, dst, fdnv, h, agg, e);
        k_fin44<<<gn, B, 0, stream>>>(h, agg, fdnv, W2, b1, n);
        k_edge4<<<ge, B, 0, stream>>>(src, dst, fdnv, h, agg, e);
        k_fin42<<<gn, B, 0, stream>>>(agg, h3, agg3, fdnv, W3, b2, n);
        k_edge2<<<ge, B, 0, stream>>>(src, dst, fdnv, h3, agg3, e);
        k_final_old<<<gn, B, 0, stream>>>(agg3, Wc, b3, bc, out_c, out_h, n);
    }
}

// Round 10
// 426.398 us; speedup vs baseline: 1.7260x; 1.0361x over previous
//
#include <hip/hip_runtime.h>
#include <math.h>

// GCN 3-layer + classifier — round 10: round-9 proven structure (442us) with
// k_linear1 rewritten as an LDS-tiled GEMV.
//
// Validated law (rounds 1-9): each address-divergent vmem / cross-lane DS
// instruction costs ~160cy of a serialized per-CU front-end. Round-9's
// sorted-run+queue aggregation dropped the bagg kernels below 73us each;
// k_linear1 (74us) became the top dispatch — its 64-lane butterfly spends
// 24 cross-lane ops per row. Round 10: 32-row LDS tiles (coalesced load,
// stride 133), thread=(row, 16-col slice), W1 slice in registers, 3-step
// shfl_xor reduction over 8 lanes (1.5 cross-lane ops/row, 16x fewer).
//
// Math identity: agg[d] = dinv[d]*( g[d] + sum_{in} g[s] ),  g = dinv*h.

#define NR 500
#define RNG 400
#define CAP 16384            // slots per bin (expect ~12800 +- 113)
#define HB 1024              // build threads
#define EPT 8                // build edges per thread
#define EPB (HB * EPT)       // 8192 edges per build block
#define SCAP 14336           // sortbin LDS buffer (mean+13 sigma)
#define Q 8                  // per-lane queue slots
#define LROWS 32             // linear1 rows per tile
#define LPAD 133             // LDS row stride (floats)

// ---------------- build (pass1: bin by dst/400) ----------------

__global__ void k_initcur(int* __restrict__ cursor) {
    int t = blockIdx.x * blockDim.x + threadIdx.x;
    if (t < NR) cursor[t * 16] = t * CAP;
}

__global__ __launch_bounds__(HB) void k_build(const int* __restrict__ src,
                                              const int* __restrict__ dst,
                                              int* __restrict__ cursor,
                                              int* __restrict__ csrp, int e) {
    __shared__ int hist[NR];
    __shared__ int scn[HB];
    __shared__ int start[NR + 1];
    __shared__ int gbase[NR];
    __shared__ int cur[NR];
    __shared__ int buf[EPB];

    int t = threadIdx.x;
    for (int i = t; i < NR; i += HB) hist[i] = 0;
    __syncthreads();

    int ds[EPT], sr[EPT];
    int base = blockIdx.x * EPB;
#pragma unroll
    for (int k = 0; k < 2; k++) {
        int idx = base + k * HB * 4 + t * 4;
        if (idx + 3 < e) {
            int4 d4 = *(const int4*)(dst + idx);
            int4 s4 = *(const int4*)(src + idx);
            ds[4 * k + 0] = d4.x; ds[4 * k + 1] = d4.y; ds[4 * k + 2] = d4.z; ds[4 * k + 3] = d4.w;
            sr[4 * k + 0] = s4.x; sr[4 * k + 1] = s4.y; sr[4 * k + 2] = s4.z; sr[4 * k + 3] = s4.w;
        } else {
#pragma unroll
            for (int j = 0; j < 4; j++) {
                int i2 = idx + j;
                if (i2 < e) { ds[4 * k + j] = dst[i2]; sr[4 * k + j] = src[i2]; }
                else ds[4 * k + j] = -1;
            }
        }
    }
#pragma unroll
    for (int k = 0; k < EPT; k++)
        if (ds[k] >= 0) atomicAdd(&hist[ds[k] / RNG], 1);
    __syncthreads();

    scn[t] = (t < NR) ? hist[t] : 0;
    __syncthreads();
    for (int off = 1; off < HB; off <<= 1) {
        int add = (t >= off) ? scn[t - off] : 0;
        __syncthreads();
        scn[t] += add;
        __syncthreads();
    }
    if (t < NR) {
        int c = hist[t];
        int st = scn[t] - c;
        start[t] = st;
        cur[t] = st;
        gbase[t] = c ? atomicAdd(&cursor[t * 16], c) : 0;
    }
    if (t == 0) start[NR] = scn[NR - 1];
    __syncthreads();

#pragma unroll
    for (int k = 0; k < EPT; k++) {
        if (ds[k] >= 0) {
            int bin = ds[k] / RNG;
            int p = atomicAdd(&cur[bin], 1);
            buf[p] = (sr[k] << 9) | (ds[k] - bin * RNG);
        }
    }
    __syncthreads();

    int total = start[NR];
    for (int j = t; j < total; j += HB) {
        int lo = 0, hi = NR;
        while (hi - lo > 1) {
            int mid = (lo + hi) >> 1;
            if (start[mid] <= j) lo = mid; else hi = mid;
        }
        int g = gbase[lo] + (j - start[lo]);
        if (g < (lo + 1) * CAP) csrp[g] = buf[j];
    }
}

// ---------------- pass2: per-bin counting sort by local dst + dinv ----------------

__global__ __launch_bounds__(1024) void k_sortbin(int* __restrict__ csrp,
                                                  const int* __restrict__ cursor,
                                                  float* __restrict__ dinv, int n) {
    __shared__ int deg[RNG];
    __shared__ int off[RNG];
    __shared__ int cur[RNG];
    __shared__ int sbuf[SCAP];
    int t = threadIdx.x, b = blockIdx.x;
    int s0 = b * CAP;
    int cnt = cursor[b * 16] - s0;
    if (cnt < 0) cnt = 0; if (cnt > CAP) cnt = CAP;

    for (int i = t; i < RNG; i += 1024) deg[i] = 0;
    __syncthreads();
    for (int j = t; j < cnt; j += 1024)
        atomicAdd(&deg[csrp[s0 + j] & 511], 1);
    __syncthreads();

    if (t < RNG) off[t] = deg[t];
    __syncthreads();
    for (int d = 1; d < RNG; d <<= 1) {
        int u = 0;
        if (t < RNG && t >= d) u = off[t - d];
        __syncthreads();
        if (t < RNG) off[t] += u;
        __syncthreads();
    }
    if (t < RNG) cur[t] = off[t] - deg[t];
    __syncthreads();

    for (int j = t; j < cnt; j += 1024) {
        int p = csrp[s0 + j];
        int r = atomicAdd(&cur[p & 511], 1);
        if (r < SCAP) sbuf[r] = p;
    }
    __syncthreads();
    int lim = (cnt < SCAP) ? cnt : SCAP;
    for (int j = t; j < lim; j += 1024)
        csrp[s0 + j] = sbuf[j];

    int basen = b * RNG;
    for (int i = t; i < RNG; i += 1024) {
        int node = basen + i;
        if (node < n) dinv[node] = rsqrtf(1.0f + (float)deg[i]);
    }
}

// ---------------- layer 1 linear: LDS-tiled, g1 = dinv * (x @ W1) ----------------

__global__ __launch_bounds__(256) void k_linear1(const float* __restrict__ x,
                                                 const float* __restrict__ W1,
                                                 const float* __restrict__ dinv,
                                                 float4* __restrict__ g1, int n) {
    __shared__ float xs[LROWS * LPAD];   // 17KB
    int t = threadIdx.x;
    int q = t & 7, r = t >> 3;           // row r (0..31), col-slice q (16 cols)
    int row0 = blockIdx.x * LROWS;

    // W1 slice for this q: rows q*16..q*16+15, each row a float4 (broadcast load)
    float4 w[16];
#pragma unroll
    for (int i = 0; i < 16; i++) w[i] = ((const float4*)W1)[q * 16 + i];

    // cooperative coalesced load: 32 rows x 128 floats = 1024 float4
    const float4* xg = (const float4*)(x + (size_t)row0 * 128);
    int maxI = (n - row0) * 32;          // float4s available in this tile
#pragma unroll
    for (int k = 0; k < 4; k++) {
        int idx = t + k * 256;
        if (idx < maxI) {
            float4 v = xg[idx];
            int rr = idx >> 5, cc = (idx & 31) << 2;
            *(float4*)&xs[rr * LPAD + cc] = v;
        }
    }
    __syncthreads();

    // compute: 16 cols per thread, 4 outputs
    float p0 = 0.f, p1 = 0.f, p2 = 0.f, p3 = 0.f;
    const float* xr = &xs[r * LPAD + q * 16];
#pragma unroll
    for (int j = 0; j < 4; j++) {
        float4 xv = *(const float4*)(xr + 4 * j);
        float4 wa = w[4 * j + 0], wb = w[4 * j + 1], wc = w[4 * j + 2], wd = w[4 * j + 3];
        p0 += xv.x * wa.x + xv.y * wb.x + xv.z * wc.x + xv.w * wd.x;
        p1 += xv.x * wa.y + xv.y * wb.y + xv.z * wc.y + xv.w * wd.y;
        p2 += xv.x * wa.z + xv.y * wb.z + xv.z * wc.z + xv.w * wd.z;
        p3 += xv.x * wa.w + xv.y * wb.w + xv.z * wc.w + xv.w * wd.w;
    }
    // reduce over the 8 q-lanes (lane bits 0..2)
#pragma unroll
    for (int off = 1; off < 8; off <<= 1) {
        p0 += __shfl_xor(p0, off, 64);
        p1 += __shfl_xor(p1, off, 64);
        p2 += __shfl_xor(p2, off, 64);
        p3 += __shfl_xor(p3, off, 64);
    }
    int row = row0 + r;
    if (q == 0 && row < n) {
        float dv = dinv[row];
        g1[row] = make_float4(dv * p0, dv * p1, dv * p2, dv * p3);
    }
}

// ---------------- sorted-run bucketed aggregation ----------------

#define PUSH4() { qd[qc * 256 + t] = cd; \
    qv[(qc * 4 + 0) * 256 + t] = a0; qv[(qc * 4 + 1) * 256 + t] = a1; \
    qv[(qc * 4 + 2) * 256 + t] = a2; qv[(qc * 4 + 3) * 256 + t] = a3; qc++; }
#define EDGE4(di, gv) { int d_ = (di) & 511; \
    if (d_ != cd) { if (cd >= 0) PUSH4(); cd = d_; a0 = gv.x; a1 = gv.y; a2 = gv.z; a3 = gv.w; } \
    else { a0 += gv.x; a1 += gv.y; a2 += gv.z; a3 += gv.w; } }
#define FLUSH4() { for (int q = 0; q < Q; q++) { if (q < qc) { int dd = qd[q * 256 + t]; \
    atomicAdd(&acc[dd * 5 + 0], qv[(q * 4 + 0) * 256 + t]); \
    atomicAdd(&acc[dd * 5 + 1], qv[(q * 4 + 1) * 256 + t]); \
    atomicAdd(&acc[dd * 5 + 2], qv[(q * 4 + 2) * 256 + t]); \
    atomicAdd(&acc[dd * 5 + 3], qv[(q * 4 + 3) * 256 + t]); } } qc = 0; }

#define EDGELOOP4() \
    int s0 = b * CAP; \
    int cnt = cursor[b * 16] - s0; if (cnt < 0) cnt = 0; if (cnt > CAP) cnt = CAP; \
    int per = (((cnt + 255) >> 8) + 3) & ~3; \
    int lo = s0 + t * per; \
    int hi = lo + per; int eE = s0 + cnt; if (hi > eE) hi = eE; \
    int cd = -1; float a0 = 0, a1 = 0, a2 = 0, a3 = 0; \
    int qc = 0; \
    for (int j = lo; j < hi; j += 4) { \
        int4 p = *(const int4*)(csrp + j); \
        int m = hi - j; \
        int i1 = (m > 1) ? p.y : p.x; \
        int i2 = (m > 2) ? p.z : p.x; \
        int i3 = (m > 3) ? p.w : p.x; \
        float4 g0 = gin[(unsigned)p.x >> 9]; \
        float4 g1 = gin[(unsigned)i1 >> 9]; \
        float4 g2 = gin[(unsigned)i2 >> 9]; \
        float4 g3 = gin[(unsigned)i3 >> 9]; \
        EDGE4(p.x, g0); \
        if (m > 1) EDGE4(i1, g1); \
        if (m > 2) EDGE4(i2, g2); \
        if (m > 3) EDGE4(i3, g3); \
        if (__any(qc >= Q - 3)) FLUSH4(); \
    } \
    if (cd >= 0) PUSH4(); \
    FLUSH4(); \
    __syncthreads();

__global__ __launch_bounds__(256) void k_bagg44s(const int* __restrict__ csrp,
                                                 const int* __restrict__ cursor,
                                                 const float* __restrict__ dinv,
                                                 const float4* __restrict__ gin,
                                                 float4* __restrict__ gout,
                                                 const float* __restrict__ W,
                                                 const float* __restrict__ bv, int n) {
    __shared__ float acc[RNG * 5];
    __shared__ float qv[Q * 4 * 256];
    __shared__ int   qd[Q * 256];
    int t = threadIdx.x, b = blockIdx.x;
    for (int i = t; i < RNG * 5; i += 256) acc[i] = 0.0f;
    __syncthreads();
    EDGELOOP4();
    int basen = b * RNG;
    for (int i = t; i < RNG; i += 256) {
        int node = basen + i;
        if (node >= n) continue;
        float4 gs = gin[node];
        float dv = dinv[node];
        float t0 = tanhf(dv * (gs.x + acc[i * 5 + 0]) + bv[0]);
        float t1 = tanhf(dv * (gs.y + acc[i * 5 + 1]) + bv[1]);
        float t2 = tanhf(dv * (gs.z + acc[i * 5 + 2]) + bv[2]);
        float t3 = tanhf(dv * (gs.w + acc[i * 5 + 3]) + bv[3]);
        float4 o;
        o.x = dv * (t0 * W[0] + t1 * W[4] + t2 * W[8]  + t3 * W[12]);
        o.y = dv * (t0 * W[1] + t1 * W[5] + t2 * W[9]  + t3 * W[13]);
        o.z = dv * (t0 * W[2] + t1 * W[6] + t2 * W[10] + t3 * W[14]);
        o.w = dv * (t0 * W[3] + t1 * W[7] + t2 * W[11] + t3 * W[15]);
        gout[node] = o;
    }
}

__global__ __launch_bounds__(256) void k_bagg42s(const int* __restrict__ csrp,
                                                 const int* __restrict__ cursor,
                                                 const float* __restrict__ dinv,
                                                 const float4* __restrict__ gin,
                                                 float2* __restrict__ gout,
                                                 const float* __restrict__ W,
                                                 const float* __restrict__ bv, int n) {
    __shared__ float acc[RNG * 5];
    __shared__ float qv[Q * 4 * 256];
    __shared__ int   qd[Q * 256];
    int t = threadIdx.x, b = blockIdx.x;
    for (int i = t; i < RNG * 5; i += 256) acc[i] = 0.0f;
    __syncthreads();
    EDGELOOP4();
    int basen = b * RNG;
    for (int i = t; i < RNG; i += 256) {
        int node = basen + i;
        if (node >= n) continue;
        float4 gs = gin[node];
        float dv = dinv[node];
        float t0 = tanhf(dv * (gs.x + acc[i * 5 + 0]) + bv[0]);
        float t1 = tanhf(dv * (gs.y + acc[i * 5 + 1]) + bv[1]);
        float t2 = tanhf(dv * (gs.z + acc[i * 5 + 2]) + bv[2]);
        float t3 = tanhf(dv * (gs.w + acc[i * 5 + 3]) + bv[3]);
        float h0 = t0 * W[0] + t1 * W[2] + t2 * W[4] + t3 * W[6];
        float h1 = t0 * W[1] + t1 * W[3] + t2 * W[5] + t3 * W[7];
        gout[node] = make_float2(dv * h0, dv * h1);
    }
}

#define PUSH2() { qd[qc * 256 + t] = cd; \
    qv[(qc * 2 + 0) * 256 + t] = a0; qv[(qc * 2 + 1) * 256 + t] = a1; qc++; }
#define EDGE2(di, gv) { int d_ = (di) & 511; \
    if (d_ != cd) { if (cd >= 0) PUSH2(); cd = d_; a0 = gv.x; a1 = gv.y; } \
    else { a0 += gv.x; a1 += gv.y; } }
#define FLUSH2() { for (int q = 0; q < Q; q++) { if (q < qc) { int dd = qd[q * 256 + t]; \
    atomicAdd(&acc[dd * 3 + 0], qv[(q * 2 + 0) * 256 + t]); \
    atomicAdd(&acc[dd * 3 + 1], qv[(q * 2 + 1) * 256 + t]); } } qc = 0; }

__global__ __launch_bounds__(256) void k_bagg2outs(const int* __restrict__ csrp,
                                                   const int* __restrict__ cursor,
                                                   const float* __restrict__ dinv,
                                                   const float2* __restrict__ gin,
                                                   const float* __restrict__ b3,
                                                   const float* __restrict__ Wc,
                                                   const float* __restrict__ bc,
                                                   float* __restrict__ out,
                                                   float2* __restrict__ hout, int n) {
    __shared__ float acc[RNG * 3];
    __shared__ float qv[Q * 2 * 256];
    __shared__ int   qd[Q * 256];
    int t = threadIdx.x, b = blockIdx.x;
    for (int i = t; i < RNG * 3; i += 256) acc[i] = 0.0f;
    __syncthreads();
    int s0 = b * CAP;
    int cnt = cursor[b * 16] - s0; if (cnt < 0) cnt = 0; if (cnt > CAP) cnt = CAP;
    int per = (((cnt + 255) >> 8) + 3) & ~3;
    int lo = s0 + t * per;
    int hi = lo + per; int eE = s0 + cnt; if (hi > eE) hi = eE;
    int cd = -1; float a0 = 0, a1 = 0;
    int qc = 0;
    for (int j = lo; j < hi; j += 4) {
        int4 p = *(const int4*)(csrp + j);
        int m = hi - j;
        int i1 = (m > 1) ? p.y : p.x;
        int i2 = (m > 2) ? p.z : p.x;
        int i3 = (m > 3) ? p.w : p.x;
        float2 g0 = gin[(unsigned)p.x >> 9];
        float2 g1 = gin[(unsigned)i1 >> 9];
        float2 g2 = gin[(unsigned)i2 >> 9];
        float2 g3 = gin[(unsigned)i3 >> 9];
        EDGE2(p.x, g0);
        if (m > 1) EDGE2(i1, g1);
        if (m > 2) EDGE2(i2, g2);
        if (m > 3) EDGE2(i3, g3);
        if (__any(qc >= Q - 3)) FLUSH2();
    }
    if (cd >= 0) PUSH2();
    FLUSH2();
    __syncthreads();
    int basen = b * RNG;
    for (int i = t; i < RNG; i += 256) {
        int node = basen + i;
        if (node >= n) continue;
        float2 gs = gin[node];
        float dv = dinv[node];
        float t0 = tanhf(dv * (gs.x + acc[i * 3 + 0]) + b3[0]);
        float t1 = tanhf(dv * (gs.y + acc[i * 3 + 1]) + b3[1]);
        hout[node] = make_float2(t0, t1);
        float4* o = (float4*)(out + (size_t)node * 16);
#pragma unroll
        for (int q = 0; q < 4; q++) {
            float4 v;
            v.x = t0 * Wc[4 * q + 0] + t1 * Wc[16 + 4 * q + 0] + bc[4 * q + 0];
            v.y = t0 * Wc[4 * q + 1] + t1 * Wc[16 + 4 * q + 1] + bc[4 * q + 1];
            v.z = t0 * Wc[4 * q + 2] + t1 * Wc[16 + 4 * q + 2] + bc[4 * q + 2];
            v.w = t0 * Wc[4 * q + 3] + t1 * Wc[16 + 4 * q + 3] + bc[4 * q + 3];
            o[q] = v;
        }
    }
}

// ---------------- fallback path (round-1 proven, push atomics) ----------------

__global__ void k_count(const int* __restrict__ dst, int* __restrict__ cnt, int e) {
    int i = blockIdx.x * blockDim.x + threadIdx.x;
    if (i < e) atomicAdd(&cnt[dst[i]], 1);
}

__global__ void k_dinv_i(const int* __restrict__ cnt, float* __restrict__ dinv, int n) {
    int i = blockIdx.x * blockDim.x + threadIdx.x;
    if (i < n) dinv[i] = rsqrtf(1.0f + (float)cnt[i]);
}

__global__ void f_linear1(const float* __restrict__ x, const float* __restrict__ W1,
                          const float* __restrict__ dinv,
                          float* __restrict__ h, float* __restrict__ agg, int n) {
    int lane = threadIdx.x & 63;
    int wave = blockIdx.x * (blockDim.x >> 6) + (threadIdx.x >> 6);
    int nwaves = gridDim.x * (blockDim.x >> 6);
    float4 w0 = ((const float4*)W1)[2 * lane];
    float4 w1 = ((const float4*)W1)[2 * lane + 1];
    for (int row = wave; row < n; row += nwaves) {
        float2 xv = ((const float2*)(x + (size_t)row * 128))[lane];
        float p0 = xv.x * w0.x + xv.y * w1.x;
        float p1 = xv.x * w0.y + xv.y * w1.y;
        float p2 = xv.x * w0.z + xv.y * w1.z;
        float p3 = xv.x * w0.w + xv.y * w1.w;
#pragma unroll
        for (int off = 32; off; off >>= 1) {
            p0 += __shfl_xor(p0, off, 64);
            p1 += __shfl_xor(p1, off, 64);
            p2 += __shfl_xor(p2, off, 64);
            p3 += __shfl_xor(p3, off, 64);
        }
        if (lane == 0) {
            float dv = dinv[row]; float dv2 = dv * dv;
            ((float4*)h)[row] = make_float4(p0, p1, p2, p3);
            ((float4*)agg)[row] = make_float4(dv2 * p0, dv2 * p1, dv2 * p2, dv2 * p3);
        }
    }
}

__global__ void k_edge4(const int* __restrict__ src, const int* __restrict__ dst,
                        const float* __restrict__ dinv, const float* __restrict__ h,
                        float* __restrict__ agg, int e) {
    int i = blockIdx.x * blockDim.x + threadIdx.x;
    if (i >= e) return;
    int s = src[i], d = dst[i];
    float w = dinv[s] * dinv[d];
    float4 hv = ((const float4*)h)[s];
    float* a = agg + 4 * (size_t)d;
    unsafeAtomicAdd(a + 0, w * hv.x);
    unsafeAtomicAdd(a + 1, w * hv.y);
    unsafeAtomicAdd(a + 2, w * hv.z);
    unsafeAtomicAdd(a + 3, w * hv.w);
}

__global__ void k_edge2(const int* __restrict__ src, const int* __restrict__ dst,
                        const float* __restrict__ dinv, const float* __restrict__ h,
                        float* __restrict__ agg, int e) {
    int i = blockIdx.x * blockDim.x + threadIdx.x;
    if (i >= e) return;
    int s = src[i], d = dst[i];
    float w = dinv[s] * dinv[d];
    float2 hv = ((const float2*)h)[s];
    float* a = agg + 2 * (size_t)d;
    unsafeAtomicAdd(a + 0, w * hv.x);
    unsafeAtomicAdd(a + 1, w * hv.y);
}

__global__ void k_fin44(float* __restrict__ h, float* __restrict__ agg,
                        const float* __restrict__ dinv,
                        const float* __restrict__ W, const float* __restrict__ b, int n) {
    int i = blockIdx.x * blockDim.x + threadIdx.x;
    if (i >= n) return;
    float4 a = ((const float4*)agg)[i];
    float t0 = tanhf(a.x + b[0]);
    float t1 = tanhf(a.y + b[1]);
    float t2 = tanhf(a.z + b[2]);
    float t3 = tanhf(a.w + b[3]);
    float hn[4];
#pragma unroll
    for (int k = 0; k < 4; k++)
        hn[k] = t0 * W[k] + t1 * W[4 + k] + t2 * W[8 + k] + t3 * W[12 + k];
    float dv = dinv[i], dv2 = dv * dv;
    ((float4*)h)[i] = make_float4(hn[0], hn[1], hn[2], hn[3]);
    ((float4*)agg)[i] = make_float4(dv2 * hn[0], dv2 * hn[1], dv2 * hn[2], dv2 * hn[3]);
}

__global__ void k_fin42(const float* __restrict__ agg, float* __restrict__ h3,
                        float* __restrict__ agg3, const float* __restrict__ dinv,
                        const float* __restrict__ W, const float* __restrict__ b, int n) {
    int i = blockIdx.x * blockDim.x + threadIdx.x;
    if (i >= n) return;
    float4 a = ((const float4*)agg)[i];
    float t0 = tanhf(a.x + b[0]);
    float t1 = tanhf(a.y + b[1]);
    float t2 = tanhf(a.z + b[2]);
    float t3 = tanhf(a.w + b[3]);
    float h0 = t0 * W[0] + t1 * W[2] + t2 * W[4] + t3 * W[6];
    float h1 = t0 * W[1] + t1 * W[3] + t2 * W[5] + t3 * W[7];
    float dv = dinv[i], dv2 = dv * dv;
    ((float2*)h3)[i] = make_float2(h0, h1);
    ((float2*)agg3)[i] = make_float2(dv2 * h0, dv2 * h1);
}

__global__ void k_final_old(const float* __restrict__ agg3,
                            const float* __restrict__ Wc, const float* __restrict__ b3,
                            const float* __restrict__ bc,
                            float* __restrict__ out, float* __restrict__ hout, int n) {
    int i = blockIdx.x * blockDim.x + threadIdx.x;
    if (i >= n) return;
    float2 a = ((const float2*)agg3)[i];
    float t0 = tanhf(a.x + b3[0]);
    float t1 = tanhf(a.y + b3[1]);
    ((float2*)hout)[i] = make_float2(t0, t1);
    float4* o = (float4*)(out + (size_t)i * 16);
#pragma unroll
    for (int q = 0; q < 4; q++) {
        float4 v;
        v.x = t0 * Wc[4 * q + 0] + t1 * Wc[16 + 4 * q + 0] + bc[4 * q + 0];
        v.y = t0 * Wc[4 * q + 1] + t1 * Wc[16 + 4 * q + 1] + bc[4 * q + 1];
        v.z = t0 * Wc[4 * q + 2] + t1 * Wc[16 + 4 * q + 2] + bc[4 * q + 2];
        v.w = t0 * Wc[4 * q + 3] + t1 * Wc[16 + 4 * q + 3] + bc[4 * q + 3];
        o[q] = v;
    }
}

// ---------------- launcher ----------------

extern "C" void kernel_launch(void* const* d_in, const int* in_sizes, int n_in,
                              void* d_out, int out_size, void* d_ws, size_t ws_size,
                              hipStream_t stream) {
    const float* x   = (const float*)d_in[0];
    const float* W1  = (const float*)d_in[1];
    const float* b1  = (const float*)d_in[2];
    const float* W2  = (const float*)d_in[3];
    const float* b2  = (const float*)d_in[4];
    const float* W3  = (const float*)d_in[5];
    const float* b3  = (const float*)d_in[6];
    const float* Wc  = (const float*)d_in[7];
    const float* bc  = (const float*)d_in[8];
    const int* eidx  = (const int*)d_in[9];

    const int n = in_sizes[0] / 128;   // 200000
    const int e = in_sizes[9] / 2;     // 6400000
    const int* src = eidx;
    const int* dst = eidx + e;

    float* out_c = (float*)d_out;                   // [n,16]
    float* out_h = (float*)d_out + 16 * (size_t)n;  // [n,2]

    const int B = 256;
    const int gn = (n + B - 1) / B;
    const int ge = (e + B - 1) / B;
    const int nbE = (e + EPB - 1) / EPB;            // build blocks

    size_t nP = ((size_t)n + 3) & ~(size_t)3;

    // fast-path workspace layout (csrp has 4096-int slack for tail overreads)
    int* csrp    = (int*)d_ws;                         // NR*CAP + 4096
    int* cursor  = csrp + (size_t)NR * CAP + 4096;     // NR*16
    float* dinv  = (float*)(cursor + NR * 16);
    float* g1    = dinv + nP;                 // 4nP
    float* g2    = g1 + 4 * nP;               // 4nP
    float* g3    = g2 + 4 * nP;               // 2nP
    size_t need  = (size_t)((char*)(g3 + 2 * nP) - (char*)d_ws);

    bool fast = (ws_size >= need) && (n <= NR * RNG) && (n < (1 << 18));

    if (fast) {
        k_initcur<<<(NR + 255) / 256, 256, 0, stream>>>(cursor);
        k_build<<<nbE, HB, 0, stream>>>(src, dst, cursor, csrp, e);
        k_sortbin<<<NR, 1024, 0, stream>>>(csrp, cursor, dinv, n);

        k_linear1<<<(n + LROWS - 1) / LROWS, 256, 0, stream>>>(x, W1, dinv, (float4*)g1, n);
        k_bagg44s<<<NR, 256, 0, stream>>>(csrp, cursor, dinv, (const float4*)g1,
                                          (float4*)g2, W2, b1, n);
        k_bagg42s<<<NR, 256, 0, stream>>>(csrp, cursor, dinv, (const float4*)g2,
                                          (float2*)g3, W3, b2, n);
        k_bagg2outs<<<NR, 256, 0, stream>>>(csrp, cursor, dinv, (const float2*)g3,
                                            b3, Wc, bc, out_c, (float2*)out_h, n);
    } else {
        // fallback: push-atomic path (~11MB ws)
        int* fcnt   = (int*)d_ws;
        float* fdnv = (float*)d_ws + nP;
        float* h    = fdnv + nP;
        float* agg  = h + 4 * nP;
        float* h3   = agg + 4 * nP;
        float* agg3 = h3 + 2 * nP;

        hipMemsetAsync(fcnt, 0, (size_t)n * sizeof(int), stream);
        k_count<<<ge, B, 0, stream>>>(dst, fcnt, e);
        k_dinv_i<<<gn, B, 0, stream>>>(fcnt, fdnv, n);
        f_linear1<<<(n + 3) / 4, B, 0, stream>>>(x, W1, fdnv, h, agg, n);
        k_edge4<<<ge, B, 0, stream>>>(src, dst, fdnv, h, agg, e);
        k_fin44<<<gn, B, 0, stream>>>(h, agg, fdnv, W2, b1, n);
        k_edge4<<<ge, B, 0, stream>>>(src, dst, fdnv, h, agg, e);
        k_fin42<<<gn, B, 0, stream>>>(agg, h3, agg3, fdnv, W3, b2, n);
        k_edge2<<<ge, B, 0, stream>>>(src, dst, fdnv, h3, agg3, e);
        k_final_old<<<gn, B, 0, stream>>>(agg3, Wc, b3, bc, out_c, out_h, n);
    }
}